// Round 1
// baseline (856.870 us; speedup 1.0000x reference)
//
#include <hip/hip_runtime.h>
#include <math.h>

#define B_ 8
#define LP_ 64
#define LS_ 512
#define L_ 576
#define D_ 768
#define H_ 12
#define HD_ 64
#define V_ 50257
#define TOPK_ 10

// ---------------------------------------------------------------------------
// Kernel 1: QKV projection. x = concat(prompt, enc) [B,L,D]; qkv = x @ Wqkv^T.
// Output scattered directly into Q/K/V tensors laid out [B,H,L,hd].
// fp32 tiled GEMM: 64x64 tile, BK=16, 256 threads, 4x4 per thread.
// ---------------------------------------------------------------------------
__global__ __launch_bounds__(256) void qkv_gemm(
    const float* __restrict__ prompt, const float* __restrict__ enc,
    const float* __restrict__ Wqkv,
    float* __restrict__ Q, float* __restrict__ Kk, float* __restrict__ Vv) {
  __shared__ float As[16][68];   // [k][m], padded
  __shared__ float Bs[16][68];   // [k][n]
  const int m0 = blockIdx.y * 64;
  const int n0 = blockIdx.x * 64;
  const int tid = threadIdx.x;
  const int tx = tid & 15, ty = tid >> 4;
  float acc[4][4] = {};

  const int rs = tid >> 2;          // staging row 0..63
  const int k4 = (tid & 3) << 2;    // staging col 0,4,8,12
  const int gm = m0 + rs;
  const int bb = gm / L_;
  const int ll = gm - bb * L_;
  const float* arow = (ll < LP_)
      ? (prompt + ((size_t)bb * LP_ + ll) * D_)
      : (enc + ((size_t)bb * LS_ + (ll - LP_)) * D_);
  const float* brow = Wqkv + (size_t)(n0 + rs) * D_;

  for (int k0 = 0; k0 < D_; k0 += 16) {
    float4 av = *(const float4*)(arow + k0 + k4);
    float4 bv = *(const float4*)(brow + k0 + k4);
    __syncthreads();  // protect previous iteration's reads
    As[k4 + 0][rs] = av.x; As[k4 + 1][rs] = av.y;
    As[k4 + 2][rs] = av.z; As[k4 + 3][rs] = av.w;
    Bs[k4 + 0][rs] = bv.x; Bs[k4 + 1][rs] = bv.y;
    Bs[k4 + 2][rs] = bv.z; Bs[k4 + 3][rs] = bv.w;
    __syncthreads();
#pragma unroll
    for (int kk = 0; kk < 16; ++kk) {
      float4 a = *(const float4*)&As[kk][ty << 2];
      float4 b = *(const float4*)&Bs[kk][tx << 2];
      float aa[4] = {a.x, a.y, a.z, a.w};
      float bbv[4] = {b.x, b.y, b.z, b.w};
#pragma unroll
      for (int i = 0; i < 4; ++i)
#pragma unroll
        for (int j = 0; j < 4; ++j)
          acc[i][j] = fmaf(aa[i], bbv[j], acc[i][j]);
    }
  }

#pragma unroll
  for (int i = 0; i < 4; ++i) {
    int m = m0 + (ty << 2) + i;
    int b = m / L_;
    int l = m - b * L_;
#pragma unroll
    for (int j = 0; j < 4; ++j) {
      int n = n0 + (tx << 2) + j;
      int part = n / D_;
      int rem = n - part * D_;
      int h = rem >> 6, e = rem & 63;
      float* dst = (part == 0) ? Q : (part == 1) ? Kk : Vv;
      dst[(((size_t)b * H_ + h) * L_ + l) * HD_ + e] = acc[i][j];
    }
  }
}

// ---------------------------------------------------------------------------
// Kernel 2: attention column sums. For each (b,h): c[k] = sum_q softmax_q[k].
// Block = (q-tile of 32 rows) x (b,h). Stores p = exp(logit) in registers
// (9 tiles x 2 rows x 4 cols = 72 VGPR), so only one pass over K tiles.
// No max-subtraction (logits ~N(0,1), max ~7 — exp safe in fp32).
// ---------------------------------------------------------------------------
__global__ __launch_bounds__(256) void attn_kernel(
    const float* __restrict__ Q, const float* __restrict__ K,
    float* __restrict__ c) {
  __shared__ float Qs[64][36];   // [e][r] transposed, 32 rows
  __shared__ float Ks[64][68];   // [e][col] transposed, 64 cols
  __shared__ float Zr[32][17];
  __shared__ float c_lds[576];
  const int qt = blockIdx.x;   // 0..17
  const int bh = blockIdx.y;   // 0..95
  const float* Qb = Q + (size_t)bh * L_ * HD_ + (size_t)qt * 32 * HD_;
  const float* Kb = K + (size_t)bh * L_ * HD_;
  const int tid = threadIdx.x;
  const int tr = tid >> 4, tc = tid & 15;  // thread: rows tr*2..+1, cols tc*4..+3

  // stage Q transposed
  for (int sI = tid; sI < 512; sI += 256) {
    int r = sI >> 4, e4 = (sI & 15) << 2;
    float4 v = *(const float4*)(Qb + (size_t)r * HD_ + e4);
    Qs[e4 + 0][r] = v.x; Qs[e4 + 1][r] = v.y;
    Qs[e4 + 2][r] = v.z; Qs[e4 + 3][r] = v.w;
  }
  for (int sI = tid; sI < 576; sI += 256) c_lds[sI] = 0.f;

  float p[9][2][4];
  float z0 = 0.f, z1 = 0.f;
#pragma unroll
  for (int kt = 0; kt < 9; ++kt) {
    __syncthreads();  // covers Q/c_lds staging (kt=0) and prior Ks reads
    for (int sI = tid; sI < 1024; sI += 256) {
      int r = sI >> 4, e4 = (sI & 15) << 2;
      float4 v = *(const float4*)(Kb + (size_t)(kt * 64 + r) * HD_ + e4);
      Ks[e4 + 0][r] = v.x; Ks[e4 + 1][r] = v.y;
      Ks[e4 + 2][r] = v.z; Ks[e4 + 3][r] = v.w;
    }
    __syncthreads();
    float a0[4] = {0.f, 0.f, 0.f, 0.f};
    float a1[4] = {0.f, 0.f, 0.f, 0.f};
#pragma unroll 8
    for (int e = 0; e < 64; ++e) {
      float2 qv = *(const float2*)&Qs[e][tr << 1];
      float4 k4 = *(const float4*)&Ks[e][tc << 2];
      float kv[4] = {k4.x, k4.y, k4.z, k4.w};
#pragma unroll
      for (int j = 0; j < 4; ++j) {
        a0[j] = fmaf(qv.x, kv[j], a0[j]);
        a1[j] = fmaf(qv.y, kv[j], a1[j]);
      }
    }
#pragma unroll
    for (int j = 0; j < 4; ++j) {
      float p0 = __expf(a0[j] * 0.125f);
      float p1 = __expf(a1[j] * 0.125f);
      p[kt][0][j] = p0; p[kt][1][j] = p1;
      z0 += p0; z1 += p1;
    }
  }
  Zr[(tr << 1) + 0][tc] = z0;
  Zr[(tr << 1) + 1][tc] = z1;
  __syncthreads();
  float Z0 = 0.f, Z1 = 0.f;
#pragma unroll
  for (int u = 0; u < 16; ++u) {
    Z0 += Zr[(tr << 1) + 0][u];
    Z1 += Zr[(tr << 1) + 1][u];
  }
  float r0 = 1.f / Z0, r1 = 1.f / Z1;
#pragma unroll
  for (int kt = 0; kt < 9; ++kt) {
#pragma unroll
    for (int j = 0; j < 4; ++j) {
      int col = kt * 64 + (tc << 2) + j;
      atomicAdd(&c_lds[col], p[kt][0][j] * r0 + p[kt][1][j] * r1);
    }
  }
  __syncthreads();
  for (int sI = tid; sI < 576; sI += 256)
    atomicAdd(&c[(size_t)bh * L_ + sI], c_lds[sI]);
}

// ---------------------------------------------------------------------------
// Kernel 3: t[b, h*64+e] = sum_k c[b,h,k] * V[b,h,k,e]
// ---------------------------------------------------------------------------
__global__ void cv_kernel(const float* __restrict__ c,
                          const float* __restrict__ Vv,
                          float* __restrict__ t) {
  const int bh = blockIdx.x;
  const int e = threadIdx.x;
  const float* cb = c + (size_t)bh * L_;
  const float* Vb = Vv + (size_t)bh * L_ * HD_;
  float acc = 0.f;
  for (int k = 0; k < L_; ++k) acc = fmaf(cb[k], Vb[(size_t)k * HD_ + e], acc);
  int b = bh / H_, h = bh - (bh / H_) * H_;
  t[(size_t)b * D_ + h * HD_ + e] = acc;
}

// ---------------------------------------------------------------------------
// Kernel 4: s[b,d] = sum_d' t[b,d'] * Wproj[d,d'] + L*bproj[d]
// ---------------------------------------------------------------------------
__global__ __launch_bounds__(768) void proj_kernel(
    const float* __restrict__ t, const float* __restrict__ Wp,
    const float* __restrict__ bp, float* __restrict__ s) {
  __shared__ float tl[768];
  const int b = blockIdx.x, d = threadIdx.x;
  tl[d] = t[(size_t)b * D_ + d];
  __syncthreads();
  float acc = (float)L_ * bp[d];
  const float* wrow = Wp + (size_t)d * D_;
  for (int dp = 0; dp < D_; ++dp) acc = fmaf(tl[dp], wrow[dp], acc);
  s[(size_t)b * D_ + d] = acc;
}

// ---------------------------------------------------------------------------
// Kernel 5: sim[b,v] = sum_d s[b,d] * word_emd[v,d]. Memory-bound (154 MB).
// Block = 256 v-rows; s staged in LDS; w staged in 32-col chunks.
// ---------------------------------------------------------------------------
__global__ __launch_bounds__(256) void sim_kernel(
    const float* __restrict__ s, const float* __restrict__ w,
    float* __restrict__ sim) {
  __shared__ float sl[8][768];    // 24.0 KB
  __shared__ float wl[256][33];   // 33.8 KB
  const int tid = threadIdx.x;
  const int v0 = blockIdx.x * 256;
  for (int i = tid; i < 1536; i += 256)
    ((float4*)&sl[0][0])[i] = ((const float4*)s)[i];
  float acc[8] = {};
  const int myv = v0 + tid;
  for (int d0 = 0; d0 < D_; d0 += 32) {
    __syncthreads();
    for (int sI = tid; sI < 2048; sI += 256) {
      int r = sI >> 3, c4 = (sI & 7) << 2;
      int vv = v0 + r;
      float4 x = make_float4(0.f, 0.f, 0.f, 0.f);
      if (vv < V_) x = *(const float4*)(w + (size_t)vv * D_ + d0 + c4);
      wl[r][c4 + 0] = x.x; wl[r][c4 + 1] = x.y;
      wl[r][c4 + 2] = x.z; wl[r][c4 + 3] = x.w;
    }
    __syncthreads();
#pragma unroll 8
    for (int dd = 0; dd < 32; ++dd) {
      float wv = wl[tid][dd];
#pragma unroll
      for (int b = 0; b < 8; ++b) acc[b] = fmaf(wv, sl[b][d0 + dd], acc[b]);
    }
  }
  if (myv < V_) {
#pragma unroll
    for (int b = 0; b < 8; ++b) sim[(size_t)b * V_ + myv] = acc[b];
  }
}

// ---------------------------------------------------------------------------
// Kernel 6: top-10 per batch by iterative max extraction (ties -> lower idx,
// matching jax.lax.top_k). Mutates sim (rewritten every call by sim_kernel).
// ---------------------------------------------------------------------------
__global__ __launch_bounds__(256) void topk_kernel(float* __restrict__ sim,
                                                   int* __restrict__ topk) {
  __shared__ float bv[256];
  __shared__ int bi[256];
  const int b = blockIdx.x, tid = threadIdx.x;
  float* row = sim + (size_t)b * V_;
  for (int k = 0; k < TOPK_; ++k) {
    float best = -INFINITY;
    int besti = V_;
    for (int v = tid; v < V_; v += 256) {
      float x = row[v];
      if (x > best) { best = x; besti = v; }  // strict > keeps lowest idx on tie
    }
    bv[tid] = best; bi[tid] = besti;
    __syncthreads();
    for (int off = 128; off > 0; off >>= 1) {
      if (tid < off) {
        float ov = bv[tid + off]; int oi = bi[tid + off];
        if (ov > bv[tid] || (ov == bv[tid] && oi < bi[tid])) {
          bv[tid] = ov; bi[tid] = oi;
        }
      }
      __syncthreads();
    }
    if (tid == 0) {
      topk[b * TOPK_ + k] = bi[0];
      row[bi[0]] = -INFINITY;
    }
    __syncthreads();
  }
}

// ---------------------------------------------------------------------------
// Kernel 7: gather word_emd rows -> output [B, K, D]
// ---------------------------------------------------------------------------
__global__ void gather_kernel(const int* __restrict__ topk,
                              const float* __restrict__ w,
                              float* __restrict__ out) {
  const int bk = blockIdx.x;
  const int idx = topk[bk];
  const int t4 = threadIdx.x << 2;
  *(float4*)(out + (size_t)bk * D_ + t4) =
      *(const float4*)(w + (size_t)idx * D_ + t4);
}

extern "C" void kernel_launch(void* const* d_in, const int* in_sizes, int n_in,
                              void* d_out, int out_size, void* d_ws,
                              size_t ws_size, hipStream_t stream) {
  const float* prompt = (const float*)d_in[0];
  const float* enc    = (const float*)d_in[1];
  const float* wemd   = (const float*)d_in[2];
  const float* Wqkv   = (const float*)d_in[3];
  const float* Wproj  = (const float*)d_in[4];
  const float* bproj  = (const float*)d_in[5];
  float* out = (float*)d_out;

  // workspace layout (floats): Q,K,V [B,H,L,hd] + c + t + s + sim + topk
  float* ws = (float*)d_ws;
  const size_t QSZ = (size_t)B_ * H_ * L_ * HD_;  // 3,538,944
  float* Q   = ws;
  float* K   = Q + QSZ;
  float* Vv  = K + QSZ;
  float* c   = Vv + QSZ;                 // 96*576 = 55,296
  float* t   = c + (size_t)B_ * H_ * L_; // 6144
  float* s   = t + (size_t)B_ * D_;      // 6144
  float* sim = s + (size_t)B_ * D_;      // 8*50257 = 402,056
  int* topk  = (int*)(sim + (size_t)B_ * V_);

  hipMemsetAsync(c, 0, (size_t)B_ * H_ * L_ * sizeof(float), stream);

  qkv_gemm<<<dim3(36, 72), 256, 0, stream>>>(prompt, enc, Wqkv, Q, K, Vv);
  attn_kernel<<<dim3(18, 96), 256, 0, stream>>>(Q, K, c);
  cv_kernel<<<96, 64, 0, stream>>>(c, Vv, t);
  proj_kernel<<<8, 768, 0, stream>>>(t, Wproj, bproj, s);
  sim_kernel<<<197, 256, 0, stream>>>(s, wemd, sim);
  topk_kernel<<<8, 256, 0, stream>>>(sim, topk);
  gather_kernel<<<80, 192, 0, stream>>>(topk, wemd, out);
}

// Round 2
// 642.871 us; speedup vs baseline: 1.3329x; 1.3329x over previous
//
#include <hip/hip_runtime.h>
#include <math.h>

#define B_ 8
#define LP_ 64
#define LS_ 512
#define L_ 576
#define D_ 768
#define H_ 12
#define HD_ 64
#define V_ 50257
#define TOPK_ 10
#define CHUNKS_ 64
#define CHUNK_SZ_ 786  // ceil(V_/CHUNKS_); 64*786 = 50304 >= 50257

// ---------------------------------------------------------------------------
// Kernel 1: QKV projection. x = concat(prompt, enc) [B,L,D]; qkv = x @ Wqkv^T.
// Output scattered directly into Q/K/V tensors laid out [B,H,L,hd].
// fp32 tiled GEMM: 64x64 tile, BK=16, 256 threads, 4x4 per thread.
// ---------------------------------------------------------------------------
__global__ __launch_bounds__(256) void qkv_gemm(
    const float* __restrict__ prompt, const float* __restrict__ enc,
    const float* __restrict__ Wqkv,
    float* __restrict__ Q, float* __restrict__ Kk, float* __restrict__ Vv) {
  __shared__ float As[16][68];   // [k][m], padded
  __shared__ float Bs[16][68];   // [k][n]
  const int m0 = blockIdx.y * 64;
  const int n0 = blockIdx.x * 64;
  const int tid = threadIdx.x;
  const int tx = tid & 15, ty = tid >> 4;
  float acc[4][4] = {};

  const int rs = tid >> 2;          // staging row 0..63
  const int k4 = (tid & 3) << 2;    // staging col 0,4,8,12
  const int gm = m0 + rs;
  const int bb = gm / L_;
  const int ll = gm - bb * L_;
  const float* arow = (ll < LP_)
      ? (prompt + ((size_t)bb * LP_ + ll) * D_)
      : (enc + ((size_t)bb * LS_ + (ll - LP_)) * D_);
  const float* brow = Wqkv + (size_t)(n0 + rs) * D_;

  for (int k0 = 0; k0 < D_; k0 += 16) {
    float4 av = *(const float4*)(arow + k0 + k4);
    float4 bv = *(const float4*)(brow + k0 + k4);
    __syncthreads();  // protect previous iteration's reads
    As[k4 + 0][rs] = av.x; As[k4 + 1][rs] = av.y;
    As[k4 + 2][rs] = av.z; As[k4 + 3][rs] = av.w;
    Bs[k4 + 0][rs] = bv.x; Bs[k4 + 1][rs] = bv.y;
    Bs[k4 + 2][rs] = bv.z; Bs[k4 + 3][rs] = bv.w;
    __syncthreads();
#pragma unroll
    for (int kk = 0; kk < 16; ++kk) {
      float4 a = *(const float4*)&As[kk][ty << 2];
      float4 b = *(const float4*)&Bs[kk][tx << 2];
      float aa[4] = {a.x, a.y, a.z, a.w};
      float bbv[4] = {b.x, b.y, b.z, b.w};
#pragma unroll
      for (int i = 0; i < 4; ++i)
#pragma unroll
        for (int j = 0; j < 4; ++j)
          acc[i][j] = fmaf(aa[i], bbv[j], acc[i][j]);
    }
  }

#pragma unroll
  for (int i = 0; i < 4; ++i) {
    int m = m0 + (ty << 2) + i;
    int b = m / L_;
    int l = m - b * L_;
#pragma unroll
    for (int j = 0; j < 4; ++j) {
      int n = n0 + (tx << 2) + j;
      int part = n / D_;
      int rem = n - part * D_;
      int h = rem >> 6, e = rem & 63;
      float* dst = (part == 0) ? Q : (part == 1) ? Kk : Vv;
      dst[(((size_t)b * H_ + h) * L_ + l) * HD_ + e] = acc[i][j];
    }
  }
}

// ---------------------------------------------------------------------------
// Kernel 2: attention column sums. For each (b,h): c[k] = sum_q softmax_q[k].
// ---------------------------------------------------------------------------
__global__ __launch_bounds__(256) void attn_kernel(
    const float* __restrict__ Q, const float* __restrict__ K,
    float* __restrict__ c) {
  __shared__ float Qs[64][36];   // [e][r] transposed, 32 rows
  __shared__ float Ks[64][68];   // [e][col] transposed, 64 cols
  __shared__ float Zr[32][17];
  __shared__ float c_lds[576];
  const int qt = blockIdx.x;   // 0..17
  const int bh = blockIdx.y;   // 0..95
  const float* Qb = Q + (size_t)bh * L_ * HD_ + (size_t)qt * 32 * HD_;
  const float* Kb = K + (size_t)bh * L_ * HD_;
  const int tid = threadIdx.x;
  const int tr = tid >> 4, tc = tid & 15;  // thread: rows tr*2..+1, cols tc*4..+3

  // stage Q transposed
  for (int sI = tid; sI < 512; sI += 256) {
    int r = sI >> 4, e4 = (sI & 15) << 2;
    float4 v = *(const float4*)(Qb + (size_t)r * HD_ + e4);
    Qs[e4 + 0][r] = v.x; Qs[e4 + 1][r] = v.y;
    Qs[e4 + 2][r] = v.z; Qs[e4 + 3][r] = v.w;
  }
  for (int sI = tid; sI < 576; sI += 256) c_lds[sI] = 0.f;

  float p[9][2][4];
  float z0 = 0.f, z1 = 0.f;
#pragma unroll
  for (int kt = 0; kt < 9; ++kt) {
    __syncthreads();  // covers Q/c_lds staging (kt=0) and prior Ks reads
    for (int sI = tid; sI < 1024; sI += 256) {
      int r = sI >> 4, e4 = (sI & 15) << 2;
      float4 v = *(const float4*)(Kb + (size_t)(kt * 64 + r) * HD_ + e4);
      Ks[e4 + 0][r] = v.x; Ks[e4 + 1][r] = v.y;
      Ks[e4 + 2][r] = v.z; Ks[e4 + 3][r] = v.w;
    }
    __syncthreads();
    float a0[4] = {0.f, 0.f, 0.f, 0.f};
    float a1[4] = {0.f, 0.f, 0.f, 0.f};
#pragma unroll 8
    for (int e = 0; e < 64; ++e) {
      float2 qv = *(const float2*)&Qs[e][tr << 1];
      float4 k4 = *(const float4*)&Ks[e][tc << 2];
      float kv[4] = {k4.x, k4.y, k4.z, k4.w};
#pragma unroll
      for (int j = 0; j < 4; ++j) {
        a0[j] = fmaf(qv.x, kv[j], a0[j]);
        a1[j] = fmaf(qv.y, kv[j], a1[j]);
      }
    }
#pragma unroll
    for (int j = 0; j < 4; ++j) {
      float p0 = __expf(a0[j] * 0.125f);
      float p1 = __expf(a1[j] * 0.125f);
      p[kt][0][j] = p0; p[kt][1][j] = p1;
      z0 += p0; z1 += p1;
    }
  }
  Zr[(tr << 1) + 0][tc] = z0;
  Zr[(tr << 1) + 1][tc] = z1;
  __syncthreads();
  float Z0 = 0.f, Z1 = 0.f;
#pragma unroll
  for (int u = 0; u < 16; ++u) {
    Z0 += Zr[(tr << 1) + 0][u];
    Z1 += Zr[(tr << 1) + 1][u];
  }
  float r0 = 1.f / Z0, r1 = 1.f / Z1;
#pragma unroll
  for (int kt = 0; kt < 9; ++kt) {
#pragma unroll
    for (int j = 0; j < 4; ++j) {
      int col = kt * 64 + (tc << 2) + j;
      atomicAdd(&c_lds[col], p[kt][0][j] * r0 + p[kt][1][j] * r1);
    }
  }
  __syncthreads();
  for (int sI = tid; sI < 576; sI += 256)
    atomicAdd(&c[(size_t)bh * L_ + sI], c_lds[sI]);
}

// ---------------------------------------------------------------------------
// Kernel 3: t[b, h*64+e] = sum_k c[b,h,k] * V[b,h,k,e]
// ---------------------------------------------------------------------------
__global__ void cv_kernel(const float* __restrict__ c,
                          const float* __restrict__ Vv,
                          float* __restrict__ t) {
  const int bh = blockIdx.x;
  const int e = threadIdx.x;
  const float* cb = c + (size_t)bh * L_;
  const float* Vb = Vv + (size_t)bh * L_ * HD_;
  float acc = 0.f;
  for (int k = 0; k < L_; ++k) acc = fmaf(cb[k], Vb[(size_t)k * HD_ + e], acc);
  int b = bh / H_, h = bh - (bh / H_) * H_;
  t[(size_t)b * D_ + h * HD_ + e] = acc;
}

// ---------------------------------------------------------------------------
// Kernel 4: s[b,d] = sum_d' t[b,d'] * Wproj[d,d'] + L*bproj[d]
// ---------------------------------------------------------------------------
__global__ __launch_bounds__(768) void proj_kernel(
    const float* __restrict__ t, const float* __restrict__ Wp,
    const float* __restrict__ bp, float* __restrict__ s) {
  __shared__ float tl[768];
  const int b = blockIdx.x, d = threadIdx.x;
  tl[d] = t[(size_t)b * D_ + d];
  __syncthreads();
  float acc = (float)L_ * bp[d];
  const float* wrow = Wp + (size_t)d * D_;
  for (int dp = 0; dp < D_; ++dp) acc = fmaf(tl[dp], wrow[dp], acc);
  s[(size_t)b * D_ + d] = acc;
}

// ---------------------------------------------------------------------------
// Kernel 5: sim[b,v] = sum_d s[b,d] * word_emd[v,d]. Memory-bound (154 MB).
// ---------------------------------------------------------------------------
__global__ __launch_bounds__(256) void sim_kernel(
    const float* __restrict__ s, const float* __restrict__ w,
    float* __restrict__ sim) {
  __shared__ float sl[8][768];    // 24.0 KB
  __shared__ float wl[256][33];   // 33.8 KB
  const int tid = threadIdx.x;
  const int v0 = blockIdx.x * 256;
  for (int i = tid; i < 1536; i += 256)
    ((float4*)&sl[0][0])[i] = ((const float4*)s)[i];
  float acc[8] = {};
  const int myv = v0 + tid;
  for (int d0 = 0; d0 < D_; d0 += 32) {
    __syncthreads();
    for (int sI = tid; sI < 2048; sI += 256) {
      int r = sI >> 3, c4 = (sI & 7) << 2;
      int vv = v0 + r;
      float4 x = make_float4(0.f, 0.f, 0.f, 0.f);
      if (vv < V_) x = *(const float4*)(w + (size_t)vv * D_ + d0 + c4);
      wl[r][c4 + 0] = x.x; wl[r][c4 + 1] = x.y;
      wl[r][c4 + 2] = x.z; wl[r][c4 + 3] = x.w;
    }
    __syncthreads();
#pragma unroll 8
    for (int dd = 0; dd < 32; ++dd) {
      float wv = wl[tid][dd];
#pragma unroll
      for (int b = 0; b < 8; ++b) acc[b] = fmaf(wv, sl[b][d0 + dd], acc[b]);
    }
  }
  if (myv < V_) {
#pragma unroll
    for (int b = 0; b < 8; ++b) sim[(size_t)b * V_ + myv] = acc[b];
  }
}

// ---------------------------------------------------------------------------
// Kernel 6a: per-chunk local top-10. Grid (CHUNKS_, B_). Each block stages
// its ~786-element chunk in LDS and extracts 10 maxima (lowest-index ties).
// ---------------------------------------------------------------------------
__global__ __launch_bounds__(256) void topk_stage1(
    const float* __restrict__ sim, float* __restrict__ cv,
    int* __restrict__ ci) {
  __shared__ float vals[CHUNK_SZ_];
  __shared__ float bv[256];
  __shared__ int bi[256];
  const int chunk = blockIdx.x, b = blockIdx.y, tid = threadIdx.x;
  const int base = chunk * CHUNK_SZ_;
  const float* row = sim + (size_t)b * V_;
  for (int i = tid; i < CHUNK_SZ_; i += 256) {
    int v = base + i;
    vals[i] = (v < V_) ? row[v] : -INFINITY;
  }
  __syncthreads();
  for (int k = 0; k < TOPK_; ++k) {
    float best = -INFINITY;
    int besti = CHUNK_SZ_;
    for (int i = tid; i < CHUNK_SZ_; i += 256) {
      float x = vals[i];
      if (x > best) { best = x; besti = i; }  // ascending scan: > keeps lowest
    }
    bv[tid] = best; bi[tid] = besti;
    __syncthreads();
    for (int off = 128; off > 0; off >>= 1) {
      if (tid < off) {
        float ov = bv[tid + off]; int oi = bi[tid + off];
        if (ov > bv[tid] || (ov == bv[tid] && oi < bi[tid])) {
          bv[tid] = ov; bi[tid] = oi;
        }
      }
      __syncthreads();
    }
    if (tid == 0) {
      int slot = (b * CHUNKS_ + chunk) * TOPK_ + k;
      cv[slot] = bv[0];
      ci[slot] = base + bi[0];
      if (bi[0] < CHUNK_SZ_) vals[bi[0]] = -INFINITY;
    }
    __syncthreads();
  }
}

// ---------------------------------------------------------------------------
// Kernel 6b: reduce 64 chunks x 10 candidates -> global top-10 per batch.
// Slot order (chunk-major, extraction-order minor) == lowest-global-index
// order on ties, so tie-breaking by slot is exact.
// ---------------------------------------------------------------------------
__global__ __launch_bounds__(256) void topk_stage2(
    const float* __restrict__ cv, const int* __restrict__ ci,
    int* __restrict__ topk) {
  const int NC = CHUNKS_ * TOPK_;  // 640
  __shared__ float vals[CHUNKS_ * TOPK_];
  __shared__ int gidx[CHUNKS_ * TOPK_];
  __shared__ float bv[256];
  __shared__ int bi[256];
  const int b = blockIdx.x, tid = threadIdx.x;
  for (int i = tid; i < NC; i += 256) {
    vals[i] = cv[(size_t)b * NC + i];
    gidx[i] = ci[(size_t)b * NC + i];
  }
  __syncthreads();
  for (int k = 0; k < TOPK_; ++k) {
    float best = -INFINITY;
    int bslot = NC;
    for (int i = tid; i < NC; i += 256) {
      float x = vals[i];
      if (x > best) { best = x; bslot = i; }  // ascending slot scan
    }
    bv[tid] = best; bi[tid] = bslot;
    __syncthreads();
    for (int off = 128; off > 0; off >>= 1) {
      if (tid < off) {
        float ov = bv[tid + off]; int oi = bi[tid + off];
        if (ov > bv[tid] || (ov == bv[tid] && oi < bi[tid])) {
          bv[tid] = ov; bi[tid] = oi;
        }
      }
      __syncthreads();
    }
    if (tid == 0) {
      int slot = bi[0];
      topk[b * TOPK_ + k] = (slot < NC) ? gidx[slot] : 0;
      if (slot < NC) vals[slot] = -INFINITY;
    }
    __syncthreads();
  }
}

// ---------------------------------------------------------------------------
// Kernel 7: gather word_emd rows -> output [B, K, D]
// ---------------------------------------------------------------------------
__global__ void gather_kernel(const int* __restrict__ topk,
                              const float* __restrict__ w,
                              float* __restrict__ out) {
  const int bk = blockIdx.x;
  const int idx = topk[bk];
  const int t4 = threadIdx.x << 2;
  *(float4*)(out + (size_t)bk * D_ + t4) =
      *(const float4*)(w + (size_t)idx * D_ + t4);
}

extern "C" void kernel_launch(void* const* d_in, const int* in_sizes, int n_in,
                              void* d_out, int out_size, void* d_ws,
                              size_t ws_size, hipStream_t stream) {
  const float* prompt = (const float*)d_in[0];
  const float* enc    = (const float*)d_in[1];
  const float* wemd   = (const float*)d_in[2];
  const float* Wqkv   = (const float*)d_in[3];
  const float* Wproj  = (const float*)d_in[4];
  const float* bproj  = (const float*)d_in[5];
  float* out = (float*)d_out;

  float* ws = (float*)d_ws;
  const size_t QSZ = (size_t)B_ * H_ * L_ * HD_;  // 3,538,944
  float* Q    = ws;
  float* K    = Q + QSZ;
  float* Vv   = K + QSZ;
  float* c    = Vv + QSZ;                 // 96*576 = 55,296
  float* t    = c + (size_t)B_ * H_ * L_; // 6144
  float* s    = t + (size_t)B_ * D_;      // 6144
  float* sim  = s + (size_t)B_ * D_;      // 8*50257 = 402,056
  float* cand_v = sim + (size_t)B_ * V_;  // 8*640 = 5120
  int* cand_i   = (int*)(cand_v + (size_t)B_ * CHUNKS_ * TOPK_);
  int* topk     = cand_i + (size_t)B_ * CHUNKS_ * TOPK_;

  hipMemsetAsync(c, 0, (size_t)B_ * H_ * L_ * sizeof(float), stream);

  qkv_gemm<<<dim3(36, 72), 256, 0, stream>>>(prompt, enc, Wqkv, Q, K, Vv);
  attn_kernel<<<dim3(18, 96), 256, 0, stream>>>(Q, K, c);
  cv_kernel<<<96, 64, 0, stream>>>(c, Vv, t);
  proj_kernel<<<8, 768, 0, stream>>>(t, Wproj, bproj, s);
  sim_kernel<<<197, 256, 0, stream>>>(s, wemd, sim);
  topk_stage1<<<dim3(CHUNKS_, B_), 256, 0, stream>>>(sim, cand_v, cand_i);
  topk_stage2<<<B_, 256, 0, stream>>>(cand_v, cand_i, topk);
  gather_kernel<<<80, 192, 0, stream>>>(topk, wemd, out);
}

// Round 3
// 525.545 us; speedup vs baseline: 1.6304x; 1.2232x over previous
//
#include <hip/hip_runtime.h>
#include <math.h>

#define B_ 8
#define LP_ 64
#define LS_ 512
#define L_ 576
#define D_ 768
#define H_ 12
#define HD_ 64
#define V_ 50257
#define TOPK_ 10
#define CHUNKS_ 64
#define CHUNK_SZ_ 786  // ceil(V_/CHUNKS_); 64*786 = 50304 >= 50257

#define M_QKV 4608   // B_*L_
#define N_QKV 2304   // 3*D_
#define K_QKV 768

typedef __attribute__((ext_vector_type(8))) short bhalf8;
typedef __attribute__((ext_vector_type(4))) float floatx4;

// ---------------------------------------------------------------------------
// bf16 hi/lo split: x = hi + lo, hi = RNE-bf16(x), lo = RNE-bf16(x - hi).
// ---------------------------------------------------------------------------
__device__ inline void bf16split(float f, unsigned short& h, unsigned short& lo) {
  unsigned int u = __float_as_uint(f);
  unsigned short hb = (unsigned short)((u + 0x7FFFu + ((u >> 16) & 1u)) >> 16);
  float hf = __uint_as_float(((unsigned int)hb) << 16);
  float lf = f - hf;
  unsigned int ul = __float_as_uint(lf);
  unsigned short lb = (unsigned short)((ul + 0x7FFFu + ((ul >> 16) & 1u)) >> 16);
  h = hb; lo = lb;
}

// ---------------------------------------------------------------------------
// Kernel 0: build Ahi/Alo [4608][768] (x = concat(prompt,enc)) and
// Bhi/Blo [2304][768] (= Wqkv) as bf16 hi/lo pairs. One float4 per thread.
// ---------------------------------------------------------------------------
__global__ __launch_bounds__(256) void convert_split(
    const float* __restrict__ prompt, const float* __restrict__ enc,
    const float* __restrict__ Wqkv,
    unsigned short* __restrict__ Ahi, unsigned short* __restrict__ Alo,
    unsigned short* __restrict__ Bhi, unsigned short* __restrict__ Blo) {
  const int NA4 = M_QKV * K_QKV / 4;  // 884736
  const int NB4 = N_QKV * K_QKV / 4;  // 442368
  int i = blockIdx.x * 256 + threadIdx.x;
  if (i >= NA4 + NB4) return;
  const float* src;
  unsigned short *dh, *dl;
  int row, c4;
  if (i < NA4) {
    row = i / (K_QKV / 4);
    c4 = (i - row * (K_QKV / 4)) * 4;
    int b = row / L_, ll = row - (row / L_) * L_;
    src = (ll < LP_) ? (prompt + ((size_t)b * LP_ + ll) * D_ + c4)
                     : (enc + ((size_t)b * LS_ + (ll - LP_)) * D_ + c4);
    dh = Ahi + (size_t)row * K_QKV + c4;
    dl = Alo + (size_t)row * K_QKV + c4;
  } else {
    int j = i - NA4;
    row = j / (K_QKV / 4);
    c4 = (j - row * (K_QKV / 4)) * 4;
    src = Wqkv + (size_t)row * K_QKV + c4;
    dh = Bhi + (size_t)row * K_QKV + c4;
    dl = Blo + (size_t)row * K_QKV + c4;
  }
  float4 v = *(const float4*)src;
  ushort4 hv, lv;
  bf16split(v.x, hv.x, lv.x);
  bf16split(v.y, hv.y, lv.y);
  bf16split(v.z, hv.z, lv.z);
  bf16split(v.w, hv.w, lv.w);
  *(ushort4*)dh = hv;
  *(ushort4*)dl = lv;
}

// ---------------------------------------------------------------------------
// Kernel 1: QKV projection as bf16 split-MFMA GEMM.
// C[m][n] = sum_k A[m][k]*B[n][k] over 3 phases: Ahi*Bhi + Alo*Bhi + Ahi*Blo.
// 128x128 tile, BK=64, 256 threads (4 waves, each a 64x64 sub-tile),
// mfma_f32_16x16x32_bf16, global_load_lds(16B) with XOR-swizzled source +
// swizzled ds_read_b128 (conflict-free). Output scattered into fp32 Q/K/V.
// ---------------------------------------------------------------------------
__global__ __launch_bounds__(256) void qkv_mfma(
    const unsigned short* __restrict__ Ahi, const unsigned short* __restrict__ Alo,
    const unsigned short* __restrict__ Bhi, const unsigned short* __restrict__ Blo,
    float* __restrict__ Q, float* __restrict__ Kk, float* __restrict__ Vv) {
  __shared__ unsigned short At[128 * 64];  // 16 KB, row-major [m][k], swizzled
  __shared__ unsigned short Bt[128 * 64];  // 16 KB, [n][k], swizzled
  const int n0 = blockIdx.x * 128;  // 0..17*128
  const int m0 = blockIdx.y * 128;  // 0..35*128
  const int tid = threadIdx.x;
  const int l = tid & 63;
  const int w = tid >> 6;          // wave 0..3
  const int wm = w >> 1, wn = w & 1;

  floatx4 acc[4][4];
#pragma unroll
  for (int i = 0; i < 4; ++i)
#pragma unroll
    for (int j = 0; j < 4; ++j) acc[i][j] = (floatx4){0.f, 0.f, 0.f, 0.f};

  // staging geometry: each global_load_lds(16B) moves 1024B = 8 rows of 128B.
  // lane l -> row r8 = l>>3 within group, LDS chunk c = l&7. Stored chunk c of
  // row r holds logical chunk c ^ (r&7)  => source chunk = (l&7) ^ r8.
  const int r8 = l >> 3;
  const int cs = (l & 7) ^ r8;          // pre-swizzled source 16B-chunk
  const int lm = l & 15;                // fragment row/col within 16
  const int lk = l >> 4;                // fragment k-group 0..3

  for (int kt = 0; kt < 36; ++kt) {
    const int phase = kt / 12;
    const int kk0 = (kt - phase * 12) * 64;
    const unsigned short* As = (phase == 1) ? Alo : Ahi;
    const unsigned short* Bs = (phase == 2) ? Blo : Bhi;
    __syncthreads();  // all waves done reading previous tile
#pragma unroll
    for (int i = 0; i < 4; ++i) {
      int row = w * 32 + i * 8;  // 8-aligned group base
      const unsigned short* ga =
          As + (size_t)(m0 + row + r8) * K_QKV + kk0 + cs * 8;
      const unsigned short* gb =
          Bs + (size_t)(n0 + row + r8) * K_QKV + kk0 + cs * 8;
      __builtin_amdgcn_global_load_lds(
          (const __attribute__((address_space(1))) unsigned int*)ga,
          (__attribute__((address_space(3))) unsigned int*)&At[row * 64],
          16, 0, 0);
      __builtin_amdgcn_global_load_lds(
          (const __attribute__((address_space(1))) unsigned int*)gb,
          (__attribute__((address_space(3))) unsigned int*)&Bt[row * 64],
          16, 0, 0);
    }
    __syncthreads();  // drains vmcnt(0): tiles visible
#pragma unroll
    for (int s = 0; s < 2; ++s) {
      bhalf8 af[4], bfr[4];
#pragma unroll
      for (int f = 0; f < 4; ++f) {
        int ma = wm * 64 + f * 16 + lm;
        int ca = (s * 4 + lk) ^ (ma & 7);
        af[f] = *(const bhalf8*)&At[ma * 64 + ca * 8];
        int nb = wn * 64 + f * 16 + lm;
        int cb = (s * 4 + lk) ^ (nb & 7);
        bfr[f] = *(const bhalf8*)&Bt[nb * 64 + cb * 8];
      }
#pragma unroll
      for (int fm = 0; fm < 4; ++fm)
#pragma unroll
        for (int fn = 0; fn < 4; ++fn)
          acc[fm][fn] = __builtin_amdgcn_mfma_f32_16x16x32_bf16(
              af[fm], bfr[fn], acc[fm][fn], 0, 0, 0);
    }
  }

  // C write: row m = (l>>4)*4 + j, col n = l&15 within each 16x16 fragment.
#pragma unroll
  for (int fm = 0; fm < 4; ++fm) {
#pragma unroll
    for (int fn = 0; fn < 4; ++fn) {
#pragma unroll
      for (int j = 0; j < 4; ++j) {
        int m = m0 + wm * 64 + fm * 16 + lk * 4 + j;
        int n = n0 + wn * 64 + fn * 16 + lm;
        int b = m / L_;
        int ll = m - b * L_;
        int part = n / D_;
        int rem = n - part * D_;
        int h = rem >> 6, e = rem & 63;
        float* dst = (part == 0) ? Q : (part == 1) ? Kk : Vv;
        dst[(((size_t)b * H_ + h) * L_ + ll) * HD_ + e] = acc[fm][fn][j];
      }
    }
  }
}

// ---------------------------------------------------------------------------
// Kernel 2: attention column sums. For each (b,h): c[k] = sum_q softmax_q[k].
// ---------------------------------------------------------------------------
__global__ __launch_bounds__(256) void attn_kernel(
    const float* __restrict__ Q, const float* __restrict__ K,
    float* __restrict__ c) {
  __shared__ float Qs[64][36];   // [e][r] transposed, 32 rows
  __shared__ float Ks[64][68];   // [e][col] transposed, 64 cols
  __shared__ float Zr[32][17];
  __shared__ float c_lds[576];
  const int qt = blockIdx.x;   // 0..17
  const int bh = blockIdx.y;   // 0..95
  const float* Qb = Q + (size_t)bh * L_ * HD_ + (size_t)qt * 32 * HD_;
  const float* Kb = K + (size_t)bh * L_ * HD_;
  const int tid = threadIdx.x;
  const int tr = tid >> 4, tc = tid & 15;  // thread: rows tr*2..+1, cols tc*4..+3

  // stage Q transposed
  for (int sI = tid; sI < 512; sI += 256) {
    int r = sI >> 4, e4 = (sI & 15) << 2;
    float4 v = *(const float4*)(Qb + (size_t)r * HD_ + e4);
    Qs[e4 + 0][r] = v.x; Qs[e4 + 1][r] = v.y;
    Qs[e4 + 2][r] = v.z; Qs[e4 + 3][r] = v.w;
  }
  for (int sI = tid; sI < 576; sI += 256) c_lds[sI] = 0.f;

  float p[9][2][4];
  float z0 = 0.f, z1 = 0.f;
#pragma unroll
  for (int kt = 0; kt < 9; ++kt) {
    __syncthreads();  // covers Q/c_lds staging (kt=0) and prior Ks reads
    for (int sI = tid; sI < 1024; sI += 256) {
      int r = sI >> 4, e4 = (sI & 15) << 2;
      float4 v = *(const float4*)(Kb + (size_t)(kt * 64 + r) * HD_ + e4);
      Ks[e4 + 0][r] = v.x; Ks[e4 + 1][r] = v.y;
      Ks[e4 + 2][r] = v.z; Ks[e4 + 3][r] = v.w;
    }
    __syncthreads();
    float a0[4] = {0.f, 0.f, 0.f, 0.f};
    float a1[4] = {0.f, 0.f, 0.f, 0.f};
#pragma unroll 8
    for (int e = 0; e < 64; ++e) {
      float2 qv = *(const float2*)&Qs[e][tr << 1];
      float4 k4 = *(const float4*)&Ks[e][tc << 2];
      float kv[4] = {k4.x, k4.y, k4.z, k4.w};
#pragma unroll
      for (int j = 0; j < 4; ++j) {
        a0[j] = fmaf(qv.x, kv[j], a0[j]);
        a1[j] = fmaf(qv.y, kv[j], a1[j]);
      }
    }
#pragma unroll
    for (int j = 0; j < 4; ++j) {
      float p0 = __expf(a0[j] * 0.125f);
      float p1 = __expf(a1[j] * 0.125f);
      p[kt][0][j] = p0; p[kt][1][j] = p1;
      z0 += p0; z1 += p1;
    }
  }
  Zr[(tr << 1) + 0][tc] = z0;
  Zr[(tr << 1) + 1][tc] = z1;
  __syncthreads();
  float Z0 = 0.f, Z1 = 0.f;
#pragma unroll
  for (int u = 0; u < 16; ++u) {
    Z0 += Zr[(tr << 1) + 0][u];
    Z1 += Zr[(tr << 1) + 1][u];
  }
  float r0 = 1.f / Z0, r1 = 1.f / Z1;
#pragma unroll
  for (int kt = 0; kt < 9; ++kt) {
#pragma unroll
    for (int j = 0; j < 4; ++j) {
      int col = kt * 64 + (tc << 2) + j;
      atomicAdd(&c_lds[col], p[kt][0][j] * r0 + p[kt][1][j] * r1);
    }
  }
  __syncthreads();
  for (int sI = tid; sI < 576; sI += 256)
    atomicAdd(&c[(size_t)bh * L_ + sI], c_lds[sI]);
}

// ---------------------------------------------------------------------------
// Kernel 3: t[b, h*64+e] = sum_k c[b,h,k] * V[b,h,k,e]
// ---------------------------------------------------------------------------
__global__ void cv_kernel(const float* __restrict__ c,
                          const float* __restrict__ Vv,
                          float* __restrict__ t) {
  const int bh = blockIdx.x;
  const int e = threadIdx.x;
  const float* cb = c + (size_t)bh * L_;
  const float* Vb = Vv + (size_t)bh * L_ * HD_;
  float acc = 0.f;
  for (int k = 0; k < L_; ++k) acc = fmaf(cb[k], Vb[(size_t)k * HD_ + e], acc);
  int b = bh / H_, h = bh - (bh / H_) * H_;
  t[(size_t)b * D_ + h * HD_ + e] = acc;
}

// ---------------------------------------------------------------------------
// Kernel 4: s[b,d] = sum_d' t[b,d'] * Wproj[d,d'] + L*bproj[d]
// ---------------------------------------------------------------------------
__global__ __launch_bounds__(768) void proj_kernel(
    const float* __restrict__ t, const float* __restrict__ Wp,
    const float* __restrict__ bp, float* __restrict__ s) {
  __shared__ float tl[768];
  const int b = blockIdx.x, d = threadIdx.x;
  tl[d] = t[(size_t)b * D_ + d];
  __syncthreads();
  float acc = (float)L_ * bp[d];
  const float* wrow = Wp + (size_t)d * D_;
  for (int dp = 0; dp < D_; ++dp) acc = fmaf(tl[dp], wrow[dp], acc);
  s[(size_t)b * D_ + d] = acc;
}

// ---------------------------------------------------------------------------
// Kernel 5: sim[b,v] = sum_d s[b,d] * word_emd[v,d]. Memory-bound (154 MB).
// ---------------------------------------------------------------------------
__global__ __launch_bounds__(256) void sim_kernel(
    const float* __restrict__ s, const float* __restrict__ w,
    float* __restrict__ sim) {
  __shared__ float sl[8][768];    // 24.0 KB
  __shared__ float wl[256][33];   // 33.8 KB
  const int tid = threadIdx.x;
  const int v0 = blockIdx.x * 256;
  for (int i = tid; i < 1536; i += 256)
    ((float4*)&sl[0][0])[i] = ((const float4*)s)[i];
  float acc[8] = {};
  const int myv = v0 + tid;
  for (int d0 = 0; d0 < D_; d0 += 32) {
    __syncthreads();
    for (int sI = tid; sI < 2048; sI += 256) {
      int r = sI >> 3, c4 = (sI & 7) << 2;
      int vv = v0 + r;
      float4 x = make_float4(0.f, 0.f, 0.f, 0.f);
      if (vv < V_) x = *(const float4*)(w + (size_t)vv * D_ + d0 + c4);
      wl[r][c4 + 0] = x.x; wl[r][c4 + 1] = x.y;
      wl[r][c4 + 2] = x.z; wl[r][c4 + 3] = x.w;
    }
    __syncthreads();
#pragma unroll 8
    for (int dd = 0; dd < 32; ++dd) {
      float wv = wl[tid][dd];
#pragma unroll
      for (int b = 0; b < 8; ++b) acc[b] = fmaf(wv, sl[b][d0 + dd], acc[b]);
    }
  }
  if (myv < V_) {
#pragma unroll
    for (int b = 0; b < 8; ++b) sim[(size_t)b * V_ + myv] = acc[b];
  }
}

// ---------------------------------------------------------------------------
// Kernel 6a: per-chunk local top-10.
// ---------------------------------------------------------------------------
__global__ __launch_bounds__(256) void topk_stage1(
    const float* __restrict__ sim, float* __restrict__ cv,
    int* __restrict__ ci) {
  __shared__ float vals[CHUNK_SZ_];
  __shared__ float bv[256];
  __shared__ int bi[256];
  const int chunk = blockIdx.x, b = blockIdx.y, tid = threadIdx.x;
  const int base = chunk * CHUNK_SZ_;
  const float* row = sim + (size_t)b * V_;
  for (int i = tid; i < CHUNK_SZ_; i += 256) {
    int v = base + i;
    vals[i] = (v < V_) ? row[v] : -INFINITY;
  }
  __syncthreads();
  for (int k = 0; k < TOPK_; ++k) {
    float best = -INFINITY;
    int besti = CHUNK_SZ_;
    for (int i = tid; i < CHUNK_SZ_; i += 256) {
      float x = vals[i];
      if (x > best) { best = x; besti = i; }
    }
    bv[tid] = best; bi[tid] = besti;
    __syncthreads();
    for (int off = 128; off > 0; off >>= 1) {
      if (tid < off) {
        float ov = bv[tid + off]; int oi = bi[tid + off];
        if (ov > bv[tid] || (ov == bv[tid] && oi < bi[tid])) {
          bv[tid] = ov; bi[tid] = oi;
        }
      }
      __syncthreads();
    }
    if (tid == 0) {
      int slot = (b * CHUNKS_ + chunk) * TOPK_ + k;
      cv[slot] = bv[0];
      ci[slot] = base + bi[0];
      if (bi[0] < CHUNK_SZ_) vals[bi[0]] = -INFINITY;
    }
    __syncthreads();
  }
}

// ---------------------------------------------------------------------------
// Kernel 6b: reduce 64 chunks x 10 candidates -> global top-10 per batch.
// ---------------------------------------------------------------------------
__global__ __launch_bounds__(256) void topk_stage2(
    const float* __restrict__ cv, const int* __restrict__ ci,
    int* __restrict__ topk) {
  const int NC = CHUNKS_ * TOPK_;  // 640
  __shared__ float vals[CHUNKS_ * TOPK_];
  __shared__ int gidx[CHUNKS_ * TOPK_];
  __shared__ float bv[256];
  __shared__ int bi[256];
  const int b = blockIdx.x, tid = threadIdx.x;
  for (int i = tid; i < NC; i += 256) {
    vals[i] = cv[(size_t)b * NC + i];
    gidx[i] = ci[(size_t)b * NC + i];
  }
  __syncthreads();
  for (int k = 0; k < TOPK_; ++k) {
    float best = -INFINITY;
    int bslot = NC;
    for (int i = tid; i < NC; i += 256) {
      float x = vals[i];
      if (x > best) { best = x; bslot = i; }
    }
    bv[tid] = best; bi[tid] = bslot;
    __syncthreads();
    for (int off = 128; off > 0; off >>= 1) {
      if (tid < off) {
        float ov = bv[tid + off]; int oi = bi[tid + off];
        if (ov > bv[tid] || (ov == bv[tid] && oi < bi[tid])) {
          bv[tid] = ov; bi[tid] = oi;
        }
      }
      __syncthreads();
    }
    if (tid == 0) {
      int slot = bi[0];
      topk[b * TOPK_ + k] = (slot < NC) ? gidx[slot] : 0;
      if (slot < NC) vals[slot] = -INFINITY;
    }
    __syncthreads();
  }
}

// ---------------------------------------------------------------------------
// Kernel 7: gather word_emd rows -> output [B, K, D]
// ---------------------------------------------------------------------------
__global__ void gather_kernel(const int* __restrict__ topk,
                              const float* __restrict__ w,
                              float* __restrict__ out) {
  const int bk = blockIdx.x;
  const int idx = topk[bk];
  const int t4 = threadIdx.x << 2;
  *(float4*)(out + (size_t)bk * D_ + t4) =
      *(const float4*)(w + (size_t)idx * D_ + t4);
}

extern "C" void kernel_launch(void* const* d_in, const int* in_sizes, int n_in,
                              void* d_out, int out_size, void* d_ws,
                              size_t ws_size, hipStream_t stream) {
  const float* prompt = (const float*)d_in[0];
  const float* enc    = (const float*)d_in[1];
  const float* wemd   = (const float*)d_in[2];
  const float* Wqkv   = (const float*)d_in[3];
  const float* Wproj  = (const float*)d_in[4];
  const float* bproj  = (const float*)d_in[5];
  float* out = (float*)d_out;

  float* ws = (float*)d_ws;
  const size_t QSZ = (size_t)B_ * H_ * L_ * HD_;  // 3,538,944
  float* Q    = ws;
  float* K    = Q + QSZ;
  float* Vv   = K + QSZ;
  float* c    = Vv + QSZ;                 // 96*576 = 55,296
  float* t    = c + (size_t)B_ * H_ * L_; // 6144
  float* s    = t + (size_t)B_ * D_;      // 6144
  float* sim  = s + (size_t)B_ * D_;      // 8*50257 = 402,056
  float* cand_v = sim + (size_t)B_ * V_;  // 8*640 = 5120
  int* cand_i   = (int*)(cand_v + (size_t)B_ * CHUNKS_ * TOPK_);
  int* topk     = cand_i + (size_t)B_ * CHUNKS_ * TOPK_;
  // bf16 hi/lo arrays (2-byte elems) after the int arrays
  unsigned short* Ahi = (unsigned short*)(topk + B_ * TOPK_ + 64);
  unsigned short* Alo = Ahi + (size_t)M_QKV * K_QKV;
  unsigned short* Bhi = Alo + (size_t)M_QKV * K_QKV;
  unsigned short* Blo = Bhi + (size_t)N_QKV * K_QKV;

  hipMemsetAsync(c, 0, (size_t)B_ * H_ * L_ * sizeof(float), stream);

  const int NCONV = (M_QKV * K_QKV + N_QKV * K_QKV) / 4;  // 1,327,104
  convert_split<<<(NCONV + 255) / 256, 256, 0, stream>>>(
      prompt, enc, Wqkv, Ahi, Alo, Bhi, Blo);
  qkv_mfma<<<dim3(N_QKV / 128, M_QKV / 128), 256, 0, stream>>>(
      Ahi, Alo, Bhi, Blo, Q, K, Vv);
  attn_kernel<<<dim3(18, 96), 256, 0, stream>>>(Q, K, c);
  cv_kernel<<<96, 64, 0, stream>>>(c, Vv, t);
  proj_kernel<<<8, 768, 0, stream>>>(t, Wproj, bproj, s);
  sim_kernel<<<197, 256, 0, stream>>>(s, wemd, sim);
  topk_stage1<<<dim3(CHUNKS_, B_), 256, 0, stream>>>(sim, cand_v, cand_i);
  topk_stage2<<<B_, 256, 0, stream>>>(cand_v, cand_i, topk);
  gather_kernel<<<80, 192, 0, stream>>>(topk, wemd, out);
}

// Round 4
// 391.754 us; speedup vs baseline: 2.1873x; 1.3415x over previous
//
#include <hip/hip_runtime.h>
#include <math.h>

#define B_ 8
#define LP_ 64
#define LS_ 512
#define L_ 576
#define D_ 768
#define H_ 12
#define HD_ 64
#define V_ 50257
#define TOPK_ 10
#define CHUNKS_ 64
#define CHUNK_SZ_ 786  // ceil(V_/CHUNKS_); 64*786 = 50304 >= 50257

#define M_QKV 4608   // B_*L_
#define N_QKV 2304   // 3*D_
#define K_QKV 768

typedef __attribute__((ext_vector_type(8))) short bhalf8;
typedef __attribute__((ext_vector_type(4))) float floatx4;

// ---------------------------------------------------------------------------
// bf16 hi/lo split: x = hi + lo, hi = RNE-bf16(x), lo = RNE-bf16(x - hi).
// ---------------------------------------------------------------------------
__device__ inline void bf16split(float f, unsigned short& h, unsigned short& lo) {
  unsigned int u = __float_as_uint(f);
  unsigned short hb = (unsigned short)((u + 0x7FFFu + ((u >> 16) & 1u)) >> 16);
  float hf = __uint_as_float(((unsigned int)hb) << 16);
  float lf = f - hf;
  unsigned int ul = __float_as_uint(lf);
  unsigned short lb = (unsigned short)((ul + 0x7FFFu + ((ul >> 16) & 1u)) >> 16);
  h = hb; lo = lb;
}

// ---------------------------------------------------------------------------
// Kernel 0: build Ahi/Alo [4608][768] (x = concat(prompt,enc)) and
// Bhi/Blo [2304][768] (= Wqkv) as bf16 hi/lo pairs. One float4 per thread.
// ---------------------------------------------------------------------------
__global__ __launch_bounds__(256) void convert_split(
    const float* __restrict__ prompt, const float* __restrict__ enc,
    const float* __restrict__ Wqkv,
    unsigned short* __restrict__ Ahi, unsigned short* __restrict__ Alo,
    unsigned short* __restrict__ Bhi, unsigned short* __restrict__ Blo) {
  const int NA4 = M_QKV * K_QKV / 4;  // 884736
  const int NB4 = N_QKV * K_QKV / 4;  // 442368
  int i = blockIdx.x * 256 + threadIdx.x;
  if (i >= NA4 + NB4) return;
  const float* src;
  unsigned short *dh, *dl;
  int row, c4;
  if (i < NA4) {
    row = i / (K_QKV / 4);
    c4 = (i - row * (K_QKV / 4)) * 4;
    int b = row / L_, ll = row - (row / L_) * L_;
    src = (ll < LP_) ? (prompt + ((size_t)b * LP_ + ll) * D_ + c4)
                     : (enc + ((size_t)b * LS_ + (ll - LP_)) * D_ + c4);
    dh = Ahi + (size_t)row * K_QKV + c4;
    dl = Alo + (size_t)row * K_QKV + c4;
  } else {
    int j = i - NA4;
    row = j / (K_QKV / 4);
    c4 = (j - row * (K_QKV / 4)) * 4;
    src = Wqkv + (size_t)row * K_QKV + c4;
    dh = Bhi + (size_t)row * K_QKV + c4;
    dl = Blo + (size_t)row * K_QKV + c4;
  }
  float4 v = *(const float4*)src;
  ushort4 hv, lv;
  bf16split(v.x, hv.x, lv.x);
  bf16split(v.y, hv.y, lv.y);
  bf16split(v.z, hv.z, lv.z);
  bf16split(v.w, hv.w, lv.w);
  *(ushort4*)dh = hv;
  *(ushort4*)dl = lv;
}

// ---------------------------------------------------------------------------
// Kernel 1: QKV projection as bf16 split-MFMA GEMM (128x128 tile, BK=64,
// 4 waves, global_load_lds + XOR swizzle). Epilogue: Q,K written as bf16
// hi/lo pairs [B,H,L,64] (feeds attn_mfma); V written fp32 (feeds cv).
// ---------------------------------------------------------------------------
__global__ __launch_bounds__(256) void qkv_mfma(
    const unsigned short* __restrict__ Ahi, const unsigned short* __restrict__ Alo,
    const unsigned short* __restrict__ Bhi, const unsigned short* __restrict__ Blo,
    unsigned short* __restrict__ Qhi, unsigned short* __restrict__ Qlo,
    unsigned short* __restrict__ Khi, unsigned short* __restrict__ Klo,
    float* __restrict__ Vv) {
  __shared__ unsigned short At[128 * 64];  // 16 KB, row-major [m][k], swizzled
  __shared__ unsigned short Bt[128 * 64];  // 16 KB, [n][k], swizzled
  const int n0 = blockIdx.x * 128;
  const int m0 = blockIdx.y * 128;
  const int tid = threadIdx.x;
  const int l = tid & 63;
  const int w = tid >> 6;          // wave 0..3
  const int wm = w >> 1, wn = w & 1;

  floatx4 acc[4][4];
#pragma unroll
  for (int i = 0; i < 4; ++i)
#pragma unroll
    for (int j = 0; j < 4; ++j) acc[i][j] = (floatx4){0.f, 0.f, 0.f, 0.f};

  const int r8 = l >> 3;
  const int cs = (l & 7) ^ r8;          // pre-swizzled source 16B-chunk
  const int lm = l & 15;                // fragment row/col within 16
  const int lk = l >> 4;                // fragment k-group 0..3

  for (int kt = 0; kt < 36; ++kt) {
    const int phase = kt / 12;
    const int kk0 = (kt - phase * 12) * 64;
    const unsigned short* As = (phase == 1) ? Alo : Ahi;
    const unsigned short* Bs = (phase == 2) ? Blo : Bhi;
    __syncthreads();  // all waves done reading previous tile
#pragma unroll
    for (int i = 0; i < 4; ++i) {
      int row = w * 32 + i * 8;  // 8-aligned group base
      const unsigned short* ga =
          As + (size_t)(m0 + row + r8) * K_QKV + kk0 + cs * 8;
      const unsigned short* gb =
          Bs + (size_t)(n0 + row + r8) * K_QKV + kk0 + cs * 8;
      __builtin_amdgcn_global_load_lds(
          (const __attribute__((address_space(1))) unsigned int*)ga,
          (__attribute__((address_space(3))) unsigned int*)&At[row * 64],
          16, 0, 0);
      __builtin_amdgcn_global_load_lds(
          (const __attribute__((address_space(1))) unsigned int*)gb,
          (__attribute__((address_space(3))) unsigned int*)&Bt[row * 64],
          16, 0, 0);
    }
    __syncthreads();  // drains vmcnt(0): tiles visible
#pragma unroll
    for (int s = 0; s < 2; ++s) {
      bhalf8 af[4], bfr[4];
#pragma unroll
      for (int f = 0; f < 4; ++f) {
        int ma = wm * 64 + f * 16 + lm;
        int ca = (s * 4 + lk) ^ (ma & 7);
        af[f] = *(const bhalf8*)&At[ma * 64 + ca * 8];
        int nb = wn * 64 + f * 16 + lm;
        int cb = (s * 4 + lk) ^ (nb & 7);
        bfr[f] = *(const bhalf8*)&Bt[nb * 64 + cb * 8];
      }
#pragma unroll
      for (int fm = 0; fm < 4; ++fm)
#pragma unroll
        for (int fn = 0; fn < 4; ++fn)
          acc[fm][fn] = __builtin_amdgcn_mfma_f32_16x16x32_bf16(
              af[fm], bfr[fn], acc[fm][fn], 0, 0, 0);
    }
  }

  // C write: row m = lk*4 + j, col n = lm within each 16x16 fragment.
  // part (Q/K/V) is block-uniform: 768 = 6 x 128-wide tiles.
#pragma unroll
  for (int fm = 0; fm < 4; ++fm) {
#pragma unroll
    for (int fn = 0; fn < 4; ++fn) {
#pragma unroll
      for (int j = 0; j < 4; ++j) {
        int m = m0 + wm * 64 + fm * 16 + lk * 4 + j;
        int n = n0 + wn * 64 + fn * 16 + lm;
        int b = m / L_;
        int ll = m - b * L_;
        int part = n / D_;
        int rem = n - part * D_;
        int h = rem >> 6, e = rem & 63;
        size_t idx = (((size_t)b * H_ + h) * L_ + ll) * HD_ + e;
        float val = acc[fm][fn][j];
        if (part == 2) {
          Vv[idx] = val;
        } else {
          unsigned short hv, lv;
          bf16split(val, hv, lv);
          if (part == 0) { Qhi[idx] = hv; Qlo[idx] = lv; }
          else           { Khi[idx] = hv; Klo[idx] = lv; }
        }
      }
    }
  }
}

// ---------------------------------------------------------------------------
// Kernel 2: attention column sums via split-bf16 MFMA.
// Block = (64-q-row tile, bh), 4 waves; wave w owns q-rows w*16..+16 x all
// 576 k. S strip kept in registers (36 frags = 144 VGPR), exp'd in place;
// Z via 16-lane shfl reduce; column sums via 4-group shfl + LDS atomics.
// ---------------------------------------------------------------------------
__global__ __launch_bounds__(256, 2) void attn_mfma(
    const unsigned short* __restrict__ Qhi, const unsigned short* __restrict__ Qlo,
    const unsigned short* __restrict__ Khi, const unsigned short* __restrict__ Klo,
    float* __restrict__ c) {
  __shared__ unsigned short Qh[64 * 64], Ql[64 * 64];  // 8 KB each
  __shared__ unsigned short Kh[64 * 64], Kl[64 * 64];
  __shared__ float c_lds[L_];
  const int qt = blockIdx.x;   // 0..8
  const int bh = blockIdx.y;   // 0..95
  const int tid = threadIdx.x;
  const int w = tid >> 6, l = tid & 63;
  const int lm = l & 15, lk = l >> 4;
  const int r8 = l >> 3;
  const int cs = (l & 7) ^ r8;

  for (int i = tid; i < L_; i += 256) c_lds[i] = 0.f;

  // stage Q tile (rows qt*64..+63): wave w stages rows w*16..+16 per buffer
  {
    const size_t gbase = ((size_t)bh * L_ + qt * 64) * HD_;
#pragma unroll
    for (int i = 0; i < 2; ++i) {
      int row = w * 16 + i * 8;
      const unsigned short* gh = Qhi + gbase + (size_t)(row + r8) * HD_ + cs * 8;
      const unsigned short* gl = Qlo + gbase + (size_t)(row + r8) * HD_ + cs * 8;
      __builtin_amdgcn_global_load_lds(
          (const __attribute__((address_space(1))) unsigned int*)gh,
          (__attribute__((address_space(3))) unsigned int*)&Qh[row * 64], 16, 0, 0);
      __builtin_amdgcn_global_load_lds(
          (const __attribute__((address_space(1))) unsigned int*)gl,
          (__attribute__((address_space(3))) unsigned int*)&Ql[row * 64], 16, 0, 0);
    }
  }

  floatx4 p[9][4];
#pragma unroll
  for (int kt = 0; kt < 9; ++kt)
#pragma unroll
    for (int fn = 0; fn < 4; ++fn) p[kt][fn] = (floatx4){0.f, 0.f, 0.f, 0.f};
  float zpart[4] = {0.f, 0.f, 0.f, 0.f};

#pragma unroll
  for (int kt = 0; kt < 9; ++kt) {
    __syncthreads();  // waves done reading previous K tile (kt=0: no-op)
    const size_t kb = ((size_t)bh * L_ + kt * 64) * HD_;
#pragma unroll
    for (int i = 0; i < 2; ++i) {
      int row = w * 16 + i * 8;
      const unsigned short* gh = Khi + kb + (size_t)(row + r8) * HD_ + cs * 8;
      const unsigned short* gl = Klo + kb + (size_t)(row + r8) * HD_ + cs * 8;
      __builtin_amdgcn_global_load_lds(
          (const __attribute__((address_space(1))) unsigned int*)gh,
          (__attribute__((address_space(3))) unsigned int*)&Kh[row * 64], 16, 0, 0);
      __builtin_amdgcn_global_load_lds(
          (const __attribute__((address_space(1))) unsigned int*)gl,
          (__attribute__((address_space(3))) unsigned int*)&Kl[row * 64], 16, 0, 0);
    }
    __syncthreads();  // drains vmcnt(0): Q (kt=0) and K tiles visible
#pragma unroll
    for (int s = 0; s < 2; ++s) {
      const int ma = w * 16 + lm;
      const int ca = (s * 4 + lk) ^ (ma & 7);
      bhalf8 ah = *(const bhalf8*)&Qh[ma * 64 + ca * 8];
      bhalf8 al = *(const bhalf8*)&Ql[ma * 64 + ca * 8];
#pragma unroll
      for (int fn = 0; fn < 4; ++fn) {
        const int nb = fn * 16 + lm;
        const int cb = (s * 4 + lk) ^ (nb & 7);
        bhalf8 bh8 = *(const bhalf8*)&Kh[nb * 64 + cb * 8];
        bhalf8 bl8 = *(const bhalf8*)&Kl[nb * 64 + cb * 8];
        p[kt][fn] = __builtin_amdgcn_mfma_f32_16x16x32_bf16(ah, bh8, p[kt][fn], 0, 0, 0);
        p[kt][fn] = __builtin_amdgcn_mfma_f32_16x16x32_bf16(al, bh8, p[kt][fn], 0, 0, 0);
        p[kt][fn] = __builtin_amdgcn_mfma_f32_16x16x32_bf16(ah, bl8, p[kt][fn], 0, 0, 0);
      }
    }
    // exp in place, accumulate row-sum partials
#pragma unroll
    for (int fn = 0; fn < 4; ++fn)
#pragma unroll
      for (int j = 0; j < 4; ++j) {
        float e = __expf(p[kt][fn][j] * 0.125f);
        p[kt][fn][j] = e;
        zpart[j] += e;
      }
  }

  // Z: reduce over the 16 lm-lanes (row r = lk*4 + j of this wave's strip)
  float invz[4];
#pragma unroll
  for (int j = 0; j < 4; ++j) {
    float z = zpart[j];
    z += __shfl_xor(z, 1);
    z += __shfl_xor(z, 2);
    z += __shfl_xor(z, 4);
    z += __shfl_xor(z, 8);
    invz[j] = 1.f / z;
  }

  // column sums: per-lane over j, then reduce over the 4 lk-groups
#pragma unroll
  for (int kt = 0; kt < 9; ++kt)
#pragma unroll
    for (int fn = 0; fn < 4; ++fn) {
      float cp = p[kt][fn][0] * invz[0] + p[kt][fn][1] * invz[1] +
                 p[kt][fn][2] * invz[2] + p[kt][fn][3] * invz[3];
      cp += __shfl_xor(cp, 16);
      cp += __shfl_xor(cp, 32);
      if (lk == 0) atomicAdd(&c_lds[kt * 64 + fn * 16 + lm], cp);
    }
  __syncthreads();
  for (int i = tid; i < L_; i += 256)
    atomicAdd(&c[(size_t)bh * L_ + i], c_lds[i]);
}

// ---------------------------------------------------------------------------
// Kernel 3: t[b, h*64+e] = sum_k c[b,h,k] * V[b,h,k,e]
// ---------------------------------------------------------------------------
__global__ void cv_kernel(const float* __restrict__ c,
                          const float* __restrict__ Vv,
                          float* __restrict__ t) {
  const int bh = blockIdx.x;
  const int e = threadIdx.x;
  const float* cb = c + (size_t)bh * L_;
  const float* Vb = Vv + (size_t)bh * L_ * HD_;
  float acc = 0.f;
  for (int k = 0; k < L_; ++k) acc = fmaf(cb[k], Vb[(size_t)k * HD_ + e], acc);
  int b = bh / H_, h = bh - (bh / H_) * H_;
  t[(size_t)b * D_ + h * HD_ + e] = acc;
}

// ---------------------------------------------------------------------------
// Kernel 4: s[b,d] = sum_d' t[b,d'] * Wproj[d,d'] + L*bproj[d]
// ---------------------------------------------------------------------------
__global__ __launch_bounds__(768) void proj_kernel(
    const float* __restrict__ t, const float* __restrict__ Wp,
    const float* __restrict__ bp, float* __restrict__ s) {
  __shared__ float tl[768];
  const int b = blockIdx.x, d = threadIdx.x;
  tl[d] = t[(size_t)b * D_ + d];
  __syncthreads();
  float acc = (float)L_ * bp[d];
  const float* wrow = Wp + (size_t)d * D_;
  for (int dp = 0; dp < D_; ++dp) acc = fmaf(tl[dp], wrow[dp], acc);
  s[(size_t)b * D_ + d] = acc;
}

// ---------------------------------------------------------------------------
// Kernel 5: sim[b,v] = sum_d s[b,d] * word_emd[v,d]. Memory-bound (154 MB).
// ---------------------------------------------------------------------------
__global__ __launch_bounds__(256) void sim_kernel(
    const float* __restrict__ s, const float* __restrict__ w,
    float* __restrict__ sim) {
  __shared__ float sl[8][768];    // 24.0 KB
  __shared__ float wl[256][33];   // 33.8 KB
  const int tid = threadIdx.x;
  const int v0 = blockIdx.x * 256;
  for (int i = tid; i < 1536; i += 256)
    ((float4*)&sl[0][0])[i] = ((const float4*)s)[i];
  float acc[8] = {};
  const int myv = v0 + tid;
  for (int d0 = 0; d0 < D_; d0 += 32) {
    __syncthreads();
    for (int sI = tid; sI < 2048; sI += 256) {
      int r = sI >> 3, c4 = (sI & 7) << 2;
      int vv = v0 + r;
      float4 x = make_float4(0.f, 0.f, 0.f, 0.f);
      if (vv < V_) x = *(const float4*)(w + (size_t)vv * D_ + d0 + c4);
      wl[r][c4 + 0] = x.x; wl[r][c4 + 1] = x.y;
      wl[r][c4 + 2] = x.z; wl[r][c4 + 3] = x.w;
    }
    __syncthreads();
#pragma unroll 8
    for (int dd = 0; dd < 32; ++dd) {
      float wv = wl[tid][dd];
#pragma unroll
      for (int b = 0; b < 8; ++b) acc[b] = fmaf(wv, sl[b][d0 + dd], acc[b]);
    }
  }
  if (myv < V_) {
#pragma unroll
    for (int b = 0; b < 8; ++b) sim[(size_t)b * V_ + myv] = acc[b];
  }
}

// ---------------------------------------------------------------------------
// Kernel 6a: per-chunk local top-10.
// ---------------------------------------------------------------------------
__global__ __launch_bounds__(256) void topk_stage1(
    const float* __restrict__ sim, float* __restrict__ cv,
    int* __restrict__ ci) {
  __shared__ float vals[CHUNK_SZ_];
  __shared__ float bv[256];
  __shared__ int bi[256];
  const int chunk = blockIdx.x, b = blockIdx.y, tid = threadIdx.x;
  const int base = chunk * CHUNK_SZ_;
  const float* row = sim + (size_t)b * V_;
  for (int i = tid; i < CHUNK_SZ_; i += 256) {
    int v = base + i;
    vals[i] = (v < V_) ? row[v] : -INFINITY;
  }
  __syncthreads();
  for (int k = 0; k < TOPK_; ++k) {
    float best = -INFINITY;
    int besti = CHUNK_SZ_;
    for (int i = tid; i < CHUNK_SZ_; i += 256) {
      float x = vals[i];
      if (x > best) { best = x; besti = i; }
    }
    bv[tid] = best; bi[tid] = besti;
    __syncthreads();
    for (int off = 128; off > 0; off >>= 1) {
      if (tid < off) {
        float ov = bv[tid + off]; int oi = bi[tid + off];
        if (ov > bv[tid] || (ov == bv[tid] && oi < bi[tid])) {
          bv[tid] = ov; bi[tid] = oi;
        }
      }
      __syncthreads();
    }
    if (tid == 0) {
      int slot = (b * CHUNKS_ + chunk) * TOPK_ + k;
      cv[slot] = bv[0];
      ci[slot] = base + bi[0];
      if (bi[0] < CHUNK_SZ_) vals[bi[0]] = -INFINITY;
    }
    __syncthreads();
  }
}

// ---------------------------------------------------------------------------
// Kernel 6b: reduce 64 chunks x 10 candidates -> global top-10 per batch.
// ---------------------------------------------------------------------------
__global__ __launch_bounds__(256) void topk_stage2(
    const float* __restrict__ cv, const int* __restrict__ ci,
    int* __restrict__ topk) {
  const int NC = CHUNKS_ * TOPK_;  // 640
  __shared__ float vals[CHUNKS_ * TOPK_];
  __shared__ int gidx[CHUNKS_ * TOPK_];
  __shared__ float bv[256];
  __shared__ int bi[256];
  const int b = blockIdx.x, tid = threadIdx.x;
  for (int i = tid; i < NC; i += 256) {
    vals[i] = cv[(size_t)b * NC + i];
    gidx[i] = ci[(size_t)b * NC + i];
  }
  __syncthreads();
  for (int k = 0; k < TOPK_; ++k) {
    float best = -INFINITY;
    int bslot = NC;
    for (int i = tid; i < NC; i += 256) {
      float x = vals[i];
      if (x > best) { best = x; bslot = i; }
    }
    bv[tid] = best; bi[tid] = bslot;
    __syncthreads();
    for (int off = 128; off > 0; off >>= 1) {
      if (tid < off) {
        float ov = bv[tid + off]; int oi = bi[tid + off];
        if (ov > bv[tid] || (ov == bv[tid] && oi < bi[tid])) {
          bv[tid] = ov; bi[tid] = oi;
        }
      }
      __syncthreads();
    }
    if (tid == 0) {
      int slot = bi[0];
      topk[b * TOPK_ + k] = (slot < NC) ? gidx[slot] : 0;
      if (slot < NC) vals[slot] = -INFINITY;
    }
    __syncthreads();
  }
}

// ---------------------------------------------------------------------------
// Kernel 7: gather word_emd rows -> output [B, K, D]
// ---------------------------------------------------------------------------
__global__ void gather_kernel(const int* __restrict__ topk,
                              const float* __restrict__ w,
                              float* __restrict__ out) {
  const int bk = blockIdx.x;
  const int idx = topk[bk];
  const int t4 = threadIdx.x << 2;
  *(float4*)(out + (size_t)bk * D_ + t4) =
      *(const float4*)(w + (size_t)idx * D_ + t4);
}

extern "C" void kernel_launch(void* const* d_in, const int* in_sizes, int n_in,
                              void* d_out, int out_size, void* d_ws,
                              size_t ws_size, hipStream_t stream) {
  const float* prompt = (const float*)d_in[0];
  const float* enc    = (const float*)d_in[1];
  const float* wemd   = (const float*)d_in[2];
  const float* Wqkv   = (const float*)d_in[3];
  const float* Wproj  = (const float*)d_in[4];
  const float* bproj  = (const float*)d_in[5];
  float* out = (float*)d_out;

  float* ws = (float*)d_ws;
  const size_t QSZ = (size_t)B_ * H_ * L_ * HD_;  // 3,538,944
  float* Vv   = ws;                        // fp32 V
  float* c    = Vv + QSZ;                  // 96*576 = 55,296
  float* t    = c + (size_t)B_ * H_ * L_;  // 6144
  float* s    = t + (size_t)B_ * D_;       // 6144
  float* sim  = s + (size_t)B_ * D_;       // 8*50257 = 402,056
  float* cand_v = sim + (size_t)B_ * V_;   // 8*640 = 5120
  int* cand_i   = (int*)(cand_v + (size_t)B_ * CHUNKS_ * TOPK_);
  int* topk     = cand_i + (size_t)B_ * CHUNKS_ * TOPK_;
  // bf16 (2-byte) arrays after the int arrays (offset keeps 16B alignment)
  unsigned short* Qhi = (unsigned short*)(topk + B_ * TOPK_ + 64);
  unsigned short* Qlo = Qhi + QSZ;
  unsigned short* Khi = Qlo + QSZ;
  unsigned short* Klo = Khi + QSZ;
  unsigned short* Ahi = Klo + QSZ;
  unsigned short* Alo = Ahi + (size_t)M_QKV * K_QKV;
  unsigned short* Bhi = Alo + (size_t)M_QKV * K_QKV;
  unsigned short* Blo = Bhi + (size_t)N_QKV * K_QKV;

  hipMemsetAsync(c, 0, (size_t)B_ * H_ * L_ * sizeof(float), stream);

  const int NCONV = (M_QKV * K_QKV + N_QKV * K_QKV) / 4;  // 1,327,104
  convert_split<<<(NCONV + 255) / 256, 256, 0, stream>>>(
      prompt, enc, Wqkv, Ahi, Alo, Bhi, Blo);
  qkv_mfma<<<dim3(N_QKV / 128, M_QKV / 128), 256, 0, stream>>>(
      Ahi, Alo, Bhi, Blo, Qhi, Qlo, Khi, Klo, Vv);
  attn_mfma<<<dim3(9, 96), 256, 0, stream>>>(Qhi, Qlo, Khi, Klo, c);
  cv_kernel<<<96, 64, 0, stream>>>(c, Vv, t);
  proj_kernel<<<8, 768, 0, stream>>>(t, Wproj, bproj, s);
  sim_kernel<<<197, 256, 0, stream>>>(s, wemd, sim);
  topk_stage1<<<dim3(CHUNKS_, B_), 256, 0, stream>>>(sim, cand_v, cand_i);
  topk_stage2<<<B_, 256, 0, stream>>>(cand_v, cand_i, topk);
  gather_kernel<<<80, 192, 0, stream>>>(topk, wemd, out);
}

// Round 5
// 313.971 us; speedup vs baseline: 2.7291x; 1.2477x over previous
//
#include <hip/hip_runtime.h>
#include <math.h>

#define B_ 8
#define LP_ 64
#define LS_ 512
#define L_ 576
#define D_ 768
#define H_ 12
#define HD_ 64
#define V_ 50257
#define TOPK_ 10
#define CHUNKS_ 64
#define CHUNK_SZ_ 786  // ceil(V_/CHUNKS_); 64*786 = 50304 >= 50257
#define NVB_ 786       // ceil(V_/64) sim v-blocks

#define M_QKV 4608   // B_*L_
#define N_QKV 2304   // 3*D_
#define K_QKV 768

typedef __attribute__((ext_vector_type(8))) short bhalf8;
typedef __attribute__((ext_vector_type(4))) float floatx4;

// ---------------------------------------------------------------------------
// bf16 hi/lo split: x = hi + lo, hi = RNE-bf16(x), lo = RNE-bf16(x - hi).
// ---------------------------------------------------------------------------
__device__ inline void bf16split(float f, unsigned short& h, unsigned short& lo) {
  unsigned int u = __float_as_uint(f);
  unsigned short hb = (unsigned short)((u + 0x7FFFu + ((u >> 16) & 1u)) >> 16);
  float hf = __uint_as_float(((unsigned int)hb) << 16);
  float lf = f - hf;
  unsigned int ul = __float_as_uint(lf);
  unsigned short lb = (unsigned short)((ul + 0x7FFFu + ((ul >> 16) & 1u)) >> 16);
  h = hb; lo = lb;
}

// ---------------------------------------------------------------------------
// Kernel 0: build Ahi/Alo [4608][768] (x = concat(prompt,enc)) and
// Bhi/Blo [2304][768] (= Wqkv) as bf16 hi/lo pairs. One float4 per thread.
// ---------------------------------------------------------------------------
__global__ __launch_bounds__(256) void convert_split(
    const float* __restrict__ prompt, const float* __restrict__ enc,
    const float* __restrict__ Wqkv,
    unsigned short* __restrict__ Ahi, unsigned short* __restrict__ Alo,
    unsigned short* __restrict__ Bhi, unsigned short* __restrict__ Blo) {
  const int NA4 = M_QKV * K_QKV / 4;  // 884736
  const int NB4 = N_QKV * K_QKV / 4;  // 442368
  int i = blockIdx.x * 256 + threadIdx.x;
  if (i >= NA4 + NB4) return;
  const float* src;
  unsigned short *dh, *dl;
  int row, c4;
  if (i < NA4) {
    row = i / (K_QKV / 4);
    c4 = (i - row * (K_QKV / 4)) * 4;
    int b = row / L_, ll = row - (row / L_) * L_;
    src = (ll < LP_) ? (prompt + ((size_t)b * LP_ + ll) * D_ + c4)
                     : (enc + ((size_t)b * LS_ + (ll - LP_)) * D_ + c4);
    dh = Ahi + (size_t)row * K_QKV + c4;
    dl = Alo + (size_t)row * K_QKV + c4;
  } else {
    int j = i - NA4;
    row = j / (K_QKV / 4);
    c4 = (j - row * (K_QKV / 4)) * 4;
    src = Wqkv + (size_t)row * K_QKV + c4;
    dh = Bhi + (size_t)row * K_QKV + c4;
    dl = Blo + (size_t)row * K_QKV + c4;
  }
  float4 v = *(const float4*)src;
  ushort4 hv, lv;
  bf16split(v.x, hv.x, lv.x);
  bf16split(v.y, hv.y, lv.y);
  bf16split(v.z, hv.z, lv.z);
  bf16split(v.w, hv.w, lv.w);
  *(ushort4*)dh = hv;
  *(ushort4*)dl = lv;
}

// ---------------------------------------------------------------------------
// Kernel 1: QKV projection as bf16 split-MFMA GEMM (128x128 tile, BK=64,
// 4 waves, global_load_lds + XOR swizzle). Epilogue: Q,K written as bf16
// hi/lo pairs [B,H,L,64] (feeds attn_mfma); V written fp32 (feeds cv).
// ---------------------------------------------------------------------------
__global__ __launch_bounds__(256) void qkv_mfma(
    const unsigned short* __restrict__ Ahi, const unsigned short* __restrict__ Alo,
    const unsigned short* __restrict__ Bhi, const unsigned short* __restrict__ Blo,
    unsigned short* __restrict__ Qhi, unsigned short* __restrict__ Qlo,
    unsigned short* __restrict__ Khi, unsigned short* __restrict__ Klo,
    float* __restrict__ Vv) {
  __shared__ unsigned short At[128 * 64];  // 16 KB, row-major [m][k], swizzled
  __shared__ unsigned short Bt[128 * 64];  // 16 KB, [n][k], swizzled
  const int n0 = blockIdx.x * 128;
  const int m0 = blockIdx.y * 128;
  const int tid = threadIdx.x;
  const int l = tid & 63;
  const int w = tid >> 6;          // wave 0..3
  const int wm = w >> 1, wn = w & 1;

  floatx4 acc[4][4];
#pragma unroll
  for (int i = 0; i < 4; ++i)
#pragma unroll
    for (int j = 0; j < 4; ++j) acc[i][j] = (floatx4){0.f, 0.f, 0.f, 0.f};

  const int r8 = l >> 3;
  const int cs = (l & 7) ^ r8;          // pre-swizzled source 16B-chunk
  const int lm = l & 15;                // fragment row/col within 16
  const int lk = l >> 4;                // fragment k-group 0..3

  for (int kt = 0; kt < 36; ++kt) {
    const int phase = kt / 12;
    const int kk0 = (kt - phase * 12) * 64;
    const unsigned short* As = (phase == 1) ? Alo : Ahi;
    const unsigned short* Bs = (phase == 2) ? Blo : Bhi;
    __syncthreads();  // all waves done reading previous tile
#pragma unroll
    for (int i = 0; i < 4; ++i) {
      int row = w * 32 + i * 8;  // 8-aligned group base
      const unsigned short* ga =
          As + (size_t)(m0 + row + r8) * K_QKV + kk0 + cs * 8;
      const unsigned short* gb =
          Bs + (size_t)(n0 + row + r8) * K_QKV + kk0 + cs * 8;
      __builtin_amdgcn_global_load_lds(
          (const __attribute__((address_space(1))) unsigned int*)ga,
          (__attribute__((address_space(3))) unsigned int*)&At[row * 64],
          16, 0, 0);
      __builtin_amdgcn_global_load_lds(
          (const __attribute__((address_space(1))) unsigned int*)gb,
          (__attribute__((address_space(3))) unsigned int*)&Bt[row * 64],
          16, 0, 0);
    }
    __syncthreads();  // drains vmcnt(0): tiles visible
#pragma unroll
    for (int s = 0; s < 2; ++s) {
      bhalf8 af[4], bfr[4];
#pragma unroll
      for (int f = 0; f < 4; ++f) {
        int ma = wm * 64 + f * 16 + lm;
        int ca = (s * 4 + lk) ^ (ma & 7);
        af[f] = *(const bhalf8*)&At[ma * 64 + ca * 8];
        int nb = wn * 64 + f * 16 + lm;
        int cb = (s * 4 + lk) ^ (nb & 7);
        bfr[f] = *(const bhalf8*)&Bt[nb * 64 + cb * 8];
      }
#pragma unroll
      for (int fm = 0; fm < 4; ++fm)
#pragma unroll
        for (int fn = 0; fn < 4; ++fn)
          acc[fm][fn] = __builtin_amdgcn_mfma_f32_16x16x32_bf16(
              af[fm], bfr[fn], acc[fm][fn], 0, 0, 0);
    }
  }

  // C write: row m = lk*4 + j, col n = lm within each 16x16 fragment.
#pragma unroll
  for (int fm = 0; fm < 4; ++fm) {
#pragma unroll
    for (int fn = 0; fn < 4; ++fn) {
#pragma unroll
      for (int j = 0; j < 4; ++j) {
        int m = m0 + wm * 64 + fm * 16 + lk * 4 + j;
        int n = n0 + wn * 64 + fn * 16 + lm;
        int b = m / L_;
        int ll = m - b * L_;
        int part = n / D_;
        int rem = n - part * D_;
        int h = rem >> 6, e = rem & 63;
        size_t idx = (((size_t)b * H_ + h) * L_ + ll) * HD_ + e;
        float val = acc[fm][fn][j];
        if (part == 2) {
          Vv[idx] = val;
        } else {
          unsigned short hv, lv;
          bf16split(val, hv, lv);
          if (part == 0) { Qhi[idx] = hv; Qlo[idx] = lv; }
          else           { Khi[idx] = hv; Klo[idx] = lv; }
        }
      }
    }
  }
}

// ---------------------------------------------------------------------------
// Kernel 2: attention column sums via split-bf16 MFMA.
// ---------------------------------------------------------------------------
__global__ __launch_bounds__(256, 2) void attn_mfma(
    const unsigned short* __restrict__ Qhi, const unsigned short* __restrict__ Qlo,
    const unsigned short* __restrict__ Khi, const unsigned short* __restrict__ Klo,
    float* __restrict__ c) {
  __shared__ unsigned short Qh[64 * 64], Ql[64 * 64];  // 8 KB each
  __shared__ unsigned short Kh[64 * 64], Kl[64 * 64];
  __shared__ float c_lds[L_];
  const int qt = blockIdx.x;   // 0..8
  const int bh = blockIdx.y;   // 0..95
  const int tid = threadIdx.x;
  const int w = tid >> 6, l = tid & 63;
  const int lm = l & 15, lk = l >> 4;
  const int r8 = l >> 3;
  const int cs = (l & 7) ^ r8;

  for (int i = tid; i < L_; i += 256) c_lds[i] = 0.f;

  {
    const size_t gbase = ((size_t)bh * L_ + qt * 64) * HD_;
#pragma unroll
    for (int i = 0; i < 2; ++i) {
      int row = w * 16 + i * 8;
      const unsigned short* gh = Qhi + gbase + (size_t)(row + r8) * HD_ + cs * 8;
      const unsigned short* gl = Qlo + gbase + (size_t)(row + r8) * HD_ + cs * 8;
      __builtin_amdgcn_global_load_lds(
          (const __attribute__((address_space(1))) unsigned int*)gh,
          (__attribute__((address_space(3))) unsigned int*)&Qh[row * 64], 16, 0, 0);
      __builtin_amdgcn_global_load_lds(
          (const __attribute__((address_space(1))) unsigned int*)gl,
          (__attribute__((address_space(3))) unsigned int*)&Ql[row * 64], 16, 0, 0);
    }
  }

  floatx4 p[9][4];
#pragma unroll
  for (int kt = 0; kt < 9; ++kt)
#pragma unroll
    for (int fn = 0; fn < 4; ++fn) p[kt][fn] = (floatx4){0.f, 0.f, 0.f, 0.f};
  float zpart[4] = {0.f, 0.f, 0.f, 0.f};

#pragma unroll
  for (int kt = 0; kt < 9; ++kt) {
    __syncthreads();  // waves done reading previous K tile (kt=0: no-op)
    const size_t kb = ((size_t)bh * L_ + kt * 64) * HD_;
#pragma unroll
    for (int i = 0; i < 2; ++i) {
      int row = w * 16 + i * 8;
      const unsigned short* gh = Khi + kb + (size_t)(row + r8) * HD_ + cs * 8;
      const unsigned short* gl = Klo + kb + (size_t)(row + r8) * HD_ + cs * 8;
      __builtin_amdgcn_global_load_lds(
          (const __attribute__((address_space(1))) unsigned int*)gh,
          (__attribute__((address_space(3))) unsigned int*)&Kh[row * 64], 16, 0, 0);
      __builtin_amdgcn_global_load_lds(
          (const __attribute__((address_space(1))) unsigned int*)gl,
          (__attribute__((address_space(3))) unsigned int*)&Kl[row * 64], 16, 0, 0);
    }
    __syncthreads();  // drains vmcnt(0): Q (kt=0) and K tiles visible
#pragma unroll
    for (int s = 0; s < 2; ++s) {
      const int ma = w * 16 + lm;
      const int ca = (s * 4 + lk) ^ (ma & 7);
      bhalf8 ah = *(const bhalf8*)&Qh[ma * 64 + ca * 8];
      bhalf8 al = *(const bhalf8*)&Ql[ma * 64 + ca * 8];
#pragma unroll
      for (int fn = 0; fn < 4; ++fn) {
        const int nb = fn * 16 + lm;
        const int cb = (s * 4 + lk) ^ (nb & 7);
        bhalf8 bh8 = *(const bhalf8*)&Kh[nb * 64 + cb * 8];
        bhalf8 bl8 = *(const bhalf8*)&Kl[nb * 64 + cb * 8];
        p[kt][fn] = __builtin_amdgcn_mfma_f32_16x16x32_bf16(ah, bh8, p[kt][fn], 0, 0, 0);
        p[kt][fn] = __builtin_amdgcn_mfma_f32_16x16x32_bf16(al, bh8, p[kt][fn], 0, 0, 0);
        p[kt][fn] = __builtin_amdgcn_mfma_f32_16x16x32_bf16(ah, bl8, p[kt][fn], 0, 0, 0);
      }
    }
#pragma unroll
    for (int fn = 0; fn < 4; ++fn)
#pragma unroll
      for (int j = 0; j < 4; ++j) {
        float e = __expf(p[kt][fn][j] * 0.125f);
        p[kt][fn][j] = e;
        zpart[j] += e;
      }
  }

  float invz[4];
#pragma unroll
  for (int j = 0; j < 4; ++j) {
    float z = zpart[j];
    z += __shfl_xor(z, 1);
    z += __shfl_xor(z, 2);
    z += __shfl_xor(z, 4);
    z += __shfl_xor(z, 8);
    invz[j] = 1.f / z;
  }

#pragma unroll
  for (int kt = 0; kt < 9; ++kt)
#pragma unroll
    for (int fn = 0; fn < 4; ++fn) {
      float cp = p[kt][fn][0] * invz[0] + p[kt][fn][1] * invz[1] +
                 p[kt][fn][2] * invz[2] + p[kt][fn][3] * invz[3];
      cp += __shfl_xor(cp, 16);
      cp += __shfl_xor(cp, 32);
      if (lk == 0) atomicAdd(&c_lds[kt * 64 + fn * 16 + lm], cp);
    }
  __syncthreads();
  for (int i = tid; i < L_; i += 256)
    atomicAdd(&c[(size_t)bh * L_ + i], c_lds[i]);
}

// ---------------------------------------------------------------------------
// Kernel 3: t[b, h*64+e] = sum_k c[b,h,k] * V[b,h,k,e]
// ---------------------------------------------------------------------------
__global__ void cv_kernel(const float* __restrict__ c,
                          const float* __restrict__ Vv,
                          float* __restrict__ t) {
  const int bh = blockIdx.x;
  const int e = threadIdx.x;
  const float* cb = c + (size_t)bh * L_;
  const float* Vb = Vv + (size_t)bh * L_ * HD_;
  float acc = 0.f;
  for (int k = 0; k < L_; ++k) acc = fmaf(cb[k], Vb[(size_t)k * HD_ + e], acc);
  int b = bh / H_, h = bh - (bh / H_) * H_;
  t[(size_t)b * D_ + h * HD_ + e] = acc;
}

// ---------------------------------------------------------------------------
// Kernel 4: s[b,d] = sum_d' t[b,d'] * Wproj[d,d'] + L*bproj[d]
// ---------------------------------------------------------------------------
__global__ __launch_bounds__(768) void proj_kernel(
    const float* __restrict__ t, const float* __restrict__ Wp,
    const float* __restrict__ bp, float* __restrict__ s) {
  __shared__ float tl[768];
  const int b = blockIdx.x, d = threadIdx.x;
  tl[d] = t[(size_t)b * D_ + d];
  __syncthreads();
  float acc = (float)L_ * bp[d];
  const float* wrow = Wp + (size_t)d * D_;
  for (int dp = 0; dp < D_; ++dp) acc = fmaf(tl[dp], wrow[dp], acc);
  s[(size_t)b * D_ + d] = acc;
}

// ---------------------------------------------------------------------------
// Kernel 5: sim[b,v] = sum_d s[b,d] * word_emd[v,d]. Memory-bound: must
// stream 154 MB of w. 786 blocks x 64 v-rows (3-4 blocks/CU). T14 split:
// issue next chunk's coalesced loads before computing current from LDS.
// wl transposed [d][row] (pad 65) -> 2-way-free b32 reads; sl broadcast b128.
// ---------------------------------------------------------------------------
__global__ __launch_bounds__(256) void sim_kernel(
    const float* __restrict__ s, const float* __restrict__ w,
    float* __restrict__ sim) {
  __shared__ float sl[8][768];   // 24 KB
  __shared__ float wl[32][65];   // 8.125 KB, [d-in-chunk][row]
  const int tid = threadIdx.x;
  const int v0 = blockIdx.x * 64;

  for (int i = tid; i < 1536; i += 256)
    ((float4*)&sl[0][0])[i] = ((const float4*)s)[i];

  // loader: 2 float4 per thread per 32-d chunk, coalesced
  const int lr0 = tid >> 3;            // rows 0..31
  const int lr1 = lr0 + 32;            // rows 32..63
  const int lc4 = (tid & 7) << 2;      // 0,4,...,28
  int vr0 = v0 + lr0; if (vr0 >= V_) vr0 = V_ - 1;
  int vr1 = v0 + lr1; if (vr1 >= V_) vr1 = V_ - 1;
  const float* wp0 = w + (size_t)vr0 * D_ + lc4;
  const float* wp1 = w + (size_t)vr1 * D_ + lc4;

  float4 stg0 = *(const float4*)(wp0);
  float4 stg1 = *(const float4*)(wp1);

  const int cr = tid & 63;   // compute row (wave = one q)
  const int q = tid >> 6;    // d-quarter within chunk
  float acc[8] = {};

  for (int ch = 0; ch < 24; ++ch) {
    __syncthreads();  // previous chunk fully read
    wl[lc4 + 0][lr0] = stg0.x; wl[lc4 + 1][lr0] = stg0.y;
    wl[lc4 + 2][lr0] = stg0.z; wl[lc4 + 3][lr0] = stg0.w;
    wl[lc4 + 0][lr1] = stg1.x; wl[lc4 + 1][lr1] = stg1.y;
    wl[lc4 + 2][lr1] = stg1.z; wl[lc4 + 3][lr1] = stg1.w;
    __syncthreads();  // tile visible
    if (ch + 1 < 24) {  // issue next chunk's loads; land during compute
      stg0 = *(const float4*)(wp0 + (ch + 1) * 32);
      stg1 = *(const float4*)(wp1 + (ch + 1) * 32);
    }
    const int d0 = ch * 32;
#pragma unroll
    for (int g = 0; g < 2; ++g) {
      const int dd = q * 8 + g * 4;
      float w0 = wl[dd + 0][cr], w1 = wl[dd + 1][cr];
      float w2 = wl[dd + 2][cr], w3 = wl[dd + 3][cr];
#pragma unroll
      for (int b = 0; b < 8; ++b) {
        float4 sv = *(const float4*)&sl[b][d0 + dd];
        acc[b] = fmaf(w0, sv.x, acc[b]);
        acc[b] = fmaf(w1, sv.y, acc[b]);
        acc[b] = fmaf(w2, sv.z, acc[b]);
        acc[b] = fmaf(w3, sv.w, acc[b]);
      }
    }
  }

  // reduce the 4 q-partials; reuse wl (2080 floats >= 4*64*8 = 2048)
  __syncthreads();
  float* red = &wl[0][0];
  float4* rp = (float4*)&red[(q * 64 + cr) * 8];
  rp[0] = make_float4(acc[0], acc[1], acc[2], acc[3]);
  rp[1] = make_float4(acc[4], acc[5], acc[6], acc[7]);
  __syncthreads();
#pragma unroll
  for (int u = 0; u < 2; ++u) {
    int o = tid * 2 + u;
    int r = o >> 3, b = o & 7;
    float sum = red[(0 * 64 + r) * 8 + b] + red[(1 * 64 + r) * 8 + b] +
                red[(2 * 64 + r) * 8 + b] + red[(3 * 64 + r) * 8 + b];
    int v = v0 + r;
    if (v < V_) sim[(size_t)b * V_ + v] = sum;
  }
}

// ---------------------------------------------------------------------------
// Kernel 6a: per-chunk local top-10.
// ---------------------------------------------------------------------------
__global__ __launch_bounds__(256) void topk_stage1(
    const float* __restrict__ sim, float* __restrict__ cv,
    int* __restrict__ ci) {
  __shared__ float vals[CHUNK_SZ_];
  __shared__ float bv[256];
  __shared__ int bi[256];
  const int chunk = blockIdx.x, b = blockIdx.y, tid = threadIdx.x;
  const int base = chunk * CHUNK_SZ_;
  const float* row = sim + (size_t)b * V_;
  for (int i = tid; i < CHUNK_SZ_; i += 256) {
    int v = base + i;
    vals[i] = (v < V_) ? row[v] : -INFINITY;
  }
  __syncthreads();
  for (int k = 0; k < TOPK_; ++k) {
    float best = -INFINITY;
    int besti = CHUNK_SZ_;
    for (int i = tid; i < CHUNK_SZ_; i += 256) {
      float x = vals[i];
      if (x > best) { best = x; besti = i; }
    }
    bv[tid] = best; bi[tid] = besti;
    __syncthreads();
    for (int off = 128; off > 0; off >>= 1) {
      if (tid < off) {
        float ov = bv[tid + off]; int oi = bi[tid + off];
        if (ov > bv[tid] || (ov == bv[tid] && oi < bi[tid])) {
          bv[tid] = ov; bi[tid] = oi;
        }
      }
      __syncthreads();
    }
    if (tid == 0) {
      int slot = (b * CHUNKS_ + chunk) * TOPK_ + k;
      cv[slot] = bv[0];
      ci[slot] = base + bi[0];
      if (bi[0] < CHUNK_SZ_) vals[bi[0]] = -INFINITY;
    }
    __syncthreads();
  }
}

// ---------------------------------------------------------------------------
// Kernel 6b: reduce 64 chunks x 10 candidates -> global top-10 per batch.
// ---------------------------------------------------------------------------
__global__ __launch_bounds__(256) void topk_stage2(
    const float* __restrict__ cv, const int* __restrict__ ci,
    int* __restrict__ topk) {
  const int NC = CHUNKS_ * TOPK_;  // 640
  __shared__ float vals[CHUNKS_ * TOPK_];
  __shared__ int gidx[CHUNKS_ * TOPK_];
  __shared__ float bv[256];
  __shared__ int bi[256];
  const int b = blockIdx.x, tid = threadIdx.x;
  for (int i = tid; i < NC; i += 256) {
    vals[i] = cv[(size_t)b * NC + i];
    gidx[i] = ci[(size_t)b * NC + i];
  }
  __syncthreads();
  for (int k = 0; k < TOPK_; ++k) {
    float best = -INFINITY;
    int bslot = NC;
    for (int i = tid; i < NC; i += 256) {
      float x = vals[i];
      if (x > best) { best = x; bslot = i; }
    }
    bv[tid] = best; bi[tid] = bslot;
    __syncthreads();
    for (int off = 128; off > 0; off >>= 1) {
      if (tid < off) {
        float ov = bv[tid + off]; int oi = bi[tid + off];
        if (ov > bv[tid] || (ov == bv[tid] && oi < bi[tid])) {
          bv[tid] = ov; bi[tid] = oi;
        }
      }
      __syncthreads();
    }
    if (tid == 0) {
      int slot = bi[0];
      topk[b * TOPK_ + k] = (slot < NC) ? gidx[slot] : 0;
      if (slot < NC) vals[slot] = -INFINITY;
    }
    __syncthreads();
  }
}

// ---------------------------------------------------------------------------
// Kernel 7: gather word_emd rows -> output [B, K, D]
// ---------------------------------------------------------------------------
__global__ void gather_kernel(const int* __restrict__ topk,
                              const float* __restrict__ w,
                              float* __restrict__ out) {
  const int bk = blockIdx.x;
  const int idx = topk[bk];
  const int t4 = threadIdx.x << 2;
  *(float4*)(out + (size_t)bk * D_ + t4) =
      *(const float4*)(w + (size_t)idx * D_ + t4);
}

extern "C" void kernel_launch(void* const* d_in, const int* in_sizes, int n_in,
                              void* d_out, int out_size, void* d_ws,
                              size_t ws_size, hipStream_t stream) {
  const float* prompt = (const float*)d_in[0];
  const float* enc    = (const float*)d_in[1];
  const float* wemd   = (const float*)d_in[2];
  const float* Wqkv   = (const float*)d_in[3];
  const float* Wproj  = (const float*)d_in[4];
  const float* bproj  = (const float*)d_in[5];
  float* out = (float*)d_out;

  float* ws = (float*)d_ws;
  const size_t QSZ = (size_t)B_ * H_ * L_ * HD_;  // 3,538,944
  float* Vv   = ws;                        // fp32 V
  float* c    = Vv + QSZ;                  // 96*576 = 55,296
  float* t    = c + (size_t)B_ * H_ * L_;  // 6144
  float* s    = t + (size_t)B_ * D_;       // 6144
  float* sim  = s + (size_t)B_ * D_;       // 8*50257 = 402,056
  float* cand_v = sim + (size_t)B_ * V_;   // 8*640 = 5120
  int* cand_i   = (int*)(cand_v + (size_t)B_ * CHUNKS_ * TOPK_);
  int* topk     = cand_i + (size_t)B_ * CHUNKS_ * TOPK_;
  unsigned short* Qhi = (unsigned short*)(topk + B_ * TOPK_ + 64);
  unsigned short* Qlo = Qhi + QSZ;
  unsigned short* Khi = Qlo + QSZ;
  unsigned short* Klo = Khi + QSZ;
  unsigned short* Ahi = Klo + QSZ;
  unsigned short* Alo = Ahi + (size_t)M_QKV * K_QKV;
  unsigned short* Bhi = Alo + (size_t)M_QKV * K_QKV;
  unsigned short* Blo = Bhi + (size_t)N_QKV * K_QKV;

  hipMemsetAsync(c, 0, (size_t)B_ * H_ * L_ * sizeof(float), stream);

  const int NCONV = (M_QKV * K_QKV + N_QKV * K_QKV) / 4;  // 1,327,104
  convert_split<<<(NCONV + 255) / 256, 256, 0, stream>>>(
      prompt, enc, Wqkv, Ahi, Alo, Bhi, Blo);
  qkv_mfma<<<dim3(N_QKV / 128, M_QKV / 128), 256, 0, stream>>>(
      Ahi, Alo, Bhi, Blo, Qhi, Qlo, Khi, Klo, Vv);
  attn_mfma<<<dim3(9, 96), 256, 0, stream>>>(Qhi, Qlo, Khi, Klo, c);
  cv_kernel<<<96, 64, 0, stream>>>(c, Vv, t);
  proj_kernel<<<8, 768, 0, stream>>>(t, Wproj, bproj, s);
  sim_kernel<<<NVB_, 256, 0, stream>>>(s, wemd, sim);
  topk_stage1<<<dim3(CHUNKS_, B_), 256, 0, stream>>>(sim, cand_v, cand_i);
  topk_stage2<<<B_, 256, 0, stream>>>(cand_v, cand_i, topk);
  gather_kernel<<<80, 192, 0, stream>>>(topk, wemd, out);
}

// Round 6
// 298.462 us; speedup vs baseline: 2.8710x; 1.0520x over previous
//
#include <hip/hip_runtime.h>
#include <math.h>

#define B_ 8
#define LP_ 64
#define LS_ 512
#define L_ 576
#define D_ 768
#define H_ 12
#define HD_ 64
#define V_ 50257
#define TOPK_ 10
#define CHUNKS_ 64
#define CHUNK_SZ_ 786  // ceil(V_/CHUNKS_); 64*786 = 50304 >= 50257
#define NVB_ 786       // ceil(V_/64) sim v-blocks

#define M_QKV 4608   // B_*L_
#define N_QKV 2304   // 3*D_
#define K_QKV 768

typedef __attribute__((ext_vector_type(8))) short bhalf8;
typedef __attribute__((ext_vector_type(4))) float floatx4;

// ---------------------------------------------------------------------------
// bf16 hi/lo split: x = hi + lo, hi = RNE-bf16(x), lo = RNE-bf16(x - hi).
// ---------------------------------------------------------------------------
__device__ inline void bf16split(float f, unsigned short& h, unsigned short& lo) {
  unsigned int u = __float_as_uint(f);
  unsigned short hb = (unsigned short)((u + 0x7FFFu + ((u >> 16) & 1u)) >> 16);
  float hf = __uint_as_float(((unsigned int)hb) << 16);
  float lf = f - hf;
  unsigned int ul = __float_as_uint(lf);
  unsigned short lb = (unsigned short)((ul + 0x7FFFu + ((ul >> 16) & 1u)) >> 16);
  h = hb; lo = lb;
}

// ---------------------------------------------------------------------------
// Kernel 0: build Ahi/Alo [4608][768] (x = concat(prompt,enc)) and
// Bhi/Blo [2304][768] (= Wqkv) as bf16 hi/lo pairs. One float4 per thread.
// ---------------------------------------------------------------------------
__global__ __launch_bounds__(256) void convert_split(
    const float* __restrict__ prompt, const float* __restrict__ enc,
    const float* __restrict__ Wqkv,
    unsigned short* __restrict__ Ahi, unsigned short* __restrict__ Alo,
    unsigned short* __restrict__ Bhi, unsigned short* __restrict__ Blo) {
  const int NA4 = M_QKV * K_QKV / 4;  // 884736
  const int NB4 = N_QKV * K_QKV / 4;  // 442368
  int i = blockIdx.x * 256 + threadIdx.x;
  if (i >= NA4 + NB4) return;
  const float* src;
  unsigned short *dh, *dl;
  int row, c4;
  if (i < NA4) {
    row = i / (K_QKV / 4);
    c4 = (i - row * (K_QKV / 4)) * 4;
    int b = row / L_, ll = row - (row / L_) * L_;
    src = (ll < LP_) ? (prompt + ((size_t)b * LP_ + ll) * D_ + c4)
                     : (enc + ((size_t)b * LS_ + (ll - LP_)) * D_ + c4);
    dh = Ahi + (size_t)row * K_QKV + c4;
    dl = Alo + (size_t)row * K_QKV + c4;
  } else {
    int j = i - NA4;
    row = j / (K_QKV / 4);
    c4 = (j - row * (K_QKV / 4)) * 4;
    src = Wqkv + (size_t)row * K_QKV + c4;
    dh = Bhi + (size_t)row * K_QKV + c4;
    dl = Blo + (size_t)row * K_QKV + c4;
  }
  float4 v = *(const float4*)src;
  ushort4 hv, lv;
  bf16split(v.x, hv.x, lv.x);
  bf16split(v.y, hv.y, lv.y);
  bf16split(v.z, hv.z, lv.z);
  bf16split(v.w, hv.w, lv.w);
  *(ushort4*)dh = hv;
  *(ushort4*)dl = lv;
}

// ---------------------------------------------------------------------------
// Kernel 1: QKV projection, split-bf16 MFMA, SINGLE fused K-pass.
// Per BK=32 step: stage Ahi/Alo/Bhi/Blo tiles (4 x 8KB LDS) and fire all
// 3 products (hi*hi + lo*hi + hi*lo) -> 48 MFMA per barrier-pair per wave.
// BK=32 swizzle: stored chunk = logical ^ ((row>>1)&3) (2-way = free).
// XCD swizzle: 648 blocks = 8*81, bijective chunked remap.
// ---------------------------------------------------------------------------
__global__ __launch_bounds__(256) void qkv_mfma(
    const unsigned short* __restrict__ Ahi, const unsigned short* __restrict__ Alo,
    const unsigned short* __restrict__ Bhi, const unsigned short* __restrict__ Blo,
    unsigned short* __restrict__ Qhi, unsigned short* __restrict__ Qlo,
    unsigned short* __restrict__ Khi, unsigned short* __restrict__ Klo,
    float* __restrict__ Vv) {
  __shared__ unsigned short Ath[128 * 32];  // 8 KB each
  __shared__ unsigned short Atl[128 * 32];
  __shared__ unsigned short Bth[128 * 32];
  __shared__ unsigned short Btl[128 * 32];
  // XCD-aware remap: grid 18 x 36 = 648 = 8 XCDs x 81 contiguous tiles
  const int flat = blockIdx.x;
  const int swz = (flat & 7) * 81 + (flat >> 3);
  const int bx = swz % 18, by = swz / 18;
  const int n0 = bx * 128, m0 = by * 128;
  const int tid = threadIdx.x;
  const int l = tid & 63;
  const int w = tid >> 6;          // wave 0..3
  const int wm = w >> 1, wn = w & 1;

  floatx4 acc[4][4];
#pragma unroll
  for (int i = 0; i < 4; ++i)
#pragma unroll
    for (int j = 0; j < 4; ++j) acc[i][j] = (floatx4){0.f, 0.f, 0.f, 0.f};

  // staging: one 1KB global_load_lds covers 16 rows of 64B. lane l -> row
  // group-row r4 = l>>2, stored chunk l&3 which must hold logical chunk
  // (l&3) ^ ((r>>1)&3) = (l&3) ^ ((l>>3)&3)  (group base is 16-aligned).
  const int r4 = l >> 2;
  const int cs = (l & 3) ^ ((l >> 3) & 3);
  const int lm = l & 15;                   // fragment row/col within 16
  const int lk = l >> 4;                   // fragment k-group 0..3
  const int cb = lk ^ ((lm >> 1) & 3);     // stored chunk for frag reads

  for (int kt = 0; kt < 24; ++kt) {
    const int kk0 = kt * 32;
    __syncthreads();  // all waves done reading previous tiles
#pragma unroll
    for (int i = 0; i < 2; ++i) {
      const int row = w * 32 + i * 16;  // 16-row group base
      const size_t ga = (size_t)(m0 + row + r4) * K_QKV + kk0 + cs * 8;
      const size_t gb = (size_t)(n0 + row + r4) * K_QKV + kk0 + cs * 8;
      __builtin_amdgcn_global_load_lds(
          (const __attribute__((address_space(1))) unsigned int*)(Ahi + ga),
          (__attribute__((address_space(3))) unsigned int*)&Ath[row * 32], 16, 0, 0);
      __builtin_amdgcn_global_load_lds(
          (const __attribute__((address_space(1))) unsigned int*)(Alo + ga),
          (__attribute__((address_space(3))) unsigned int*)&Atl[row * 32], 16, 0, 0);
      __builtin_amdgcn_global_load_lds(
          (const __attribute__((address_space(1))) unsigned int*)(Bhi + gb),
          (__attribute__((address_space(3))) unsigned int*)&Bth[row * 32], 16, 0, 0);
      __builtin_amdgcn_global_load_lds(
          (const __attribute__((address_space(1))) unsigned int*)(Blo + gb),
          (__attribute__((address_space(3))) unsigned int*)&Btl[row * 32], 16, 0, 0);
    }
    __syncthreads();  // drains vmcnt(0): tiles visible

    bhalf8 ah[4], al[4], bh8[4], bl8[4];
#pragma unroll
    for (int f = 0; f < 4; ++f) {
      const int ma = wm * 64 + f * 16 + lm;
      const int oa = ma * 32 + cb * 8;
      ah[f] = *(const bhalf8*)&Ath[oa];
      al[f] = *(const bhalf8*)&Atl[oa];
      const int nb = wn * 64 + f * 16 + lm;
      const int ob = nb * 32 + cb * 8;
      bh8[f] = *(const bhalf8*)&Bth[ob];
      bl8[f] = *(const bhalf8*)&Btl[ob];
    }
#pragma unroll
    for (int fm = 0; fm < 4; ++fm)
#pragma unroll
      for (int fn = 0; fn < 4; ++fn) {
        acc[fm][fn] = __builtin_amdgcn_mfma_f32_16x16x32_bf16(
            ah[fm], bh8[fn], acc[fm][fn], 0, 0, 0);
        acc[fm][fn] = __builtin_amdgcn_mfma_f32_16x16x32_bf16(
            al[fm], bh8[fn], acc[fm][fn], 0, 0, 0);
        acc[fm][fn] = __builtin_amdgcn_mfma_f32_16x16x32_bf16(
            ah[fm], bl8[fn], acc[fm][fn], 0, 0, 0);
      }
  }

  // C write: row m = lk*4 + j, col n = lm within each 16x16 fragment.
#pragma unroll
  for (int fm = 0; fm < 4; ++fm) {
#pragma unroll
    for (int fn = 0; fn < 4; ++fn) {
#pragma unroll
      for (int j = 0; j < 4; ++j) {
        int m = m0 + wm * 64 + fm * 16 + lk * 4 + j;
        int n = n0 + wn * 64 + fn * 16 + lm;
        int b = m / L_;
        int ll = m - b * L_;
        int part = n / D_;
        int rem = n - part * D_;
        int h = rem >> 6, e = rem & 63;
        size_t idx = (((size_t)b * H_ + h) * L_ + ll) * HD_ + e;
        float val = acc[fm][fn][j];
        if (part == 2) {
          Vv[idx] = val;
        } else {
          unsigned short hv, lv;
          bf16split(val, hv, lv);
          if (part == 0) { Qhi[idx] = hv; Qlo[idx] = lv; }
          else           { Khi[idx] = hv; Klo[idx] = lv; }
        }
      }
    }
  }
}

// ---------------------------------------------------------------------------
// Kernel 2: attention column sums via split-bf16 MFMA.
// ---------------------------------------------------------------------------
__global__ __launch_bounds__(256, 2) void attn_mfma(
    const unsigned short* __restrict__ Qhi, const unsigned short* __restrict__ Qlo,
    const unsigned short* __restrict__ Khi, const unsigned short* __restrict__ Klo,
    float* __restrict__ c) {
  __shared__ unsigned short Qh[64 * 64], Ql[64 * 64];  // 8 KB each
  __shared__ unsigned short Kh[64 * 64], Kl[64 * 64];
  __shared__ float c_lds[L_];
  const int qt = blockIdx.x;   // 0..8
  const int bh = blockIdx.y;   // 0..95
  const int tid = threadIdx.x;
  const int w = tid >> 6, l = tid & 63;
  const int lm = l & 15, lk = l >> 4;
  const int r8 = l >> 3;
  const int cs = (l & 7) ^ r8;

  for (int i = tid; i < L_; i += 256) c_lds[i] = 0.f;

  {
    const size_t gbase = ((size_t)bh * L_ + qt * 64) * HD_;
#pragma unroll
    for (int i = 0; i < 2; ++i) {
      int row = w * 16 + i * 8;
      const unsigned short* gh = Qhi + gbase + (size_t)(row + r8) * HD_ + cs * 8;
      const unsigned short* gl = Qlo + gbase + (size_t)(row + r8) * HD_ + cs * 8;
      __builtin_amdgcn_global_load_lds(
          (const __attribute__((address_space(1))) unsigned int*)gh,
          (__attribute__((address_space(3))) unsigned int*)&Qh[row * 64], 16, 0, 0);
      __builtin_amdgcn_global_load_lds(
          (const __attribute__((address_space(1))) unsigned int*)gl,
          (__attribute__((address_space(3))) unsigned int*)&Ql[row * 64], 16, 0, 0);
    }
  }

  floatx4 p[9][4];
#pragma unroll
  for (int kt = 0; kt < 9; ++kt)
#pragma unroll
    for (int fn = 0; fn < 4; ++fn) p[kt][fn] = (floatx4){0.f, 0.f, 0.f, 0.f};
  float zpart[4] = {0.f, 0.f, 0.f, 0.f};

#pragma unroll
  for (int kt = 0; kt < 9; ++kt) {
    __syncthreads();  // waves done reading previous K tile (kt=0: no-op)
    const size_t kb = ((size_t)bh * L_ + kt * 64) * HD_;
#pragma unroll
    for (int i = 0; i < 2; ++i) {
      int row = w * 16 + i * 8;
      const unsigned short* gh = Khi + kb + (size_t)(row + r8) * HD_ + cs * 8;
      const unsigned short* gl = Klo + kb + (size_t)(row + r8) * HD_ + cs * 8;
      __builtin_amdgcn_global_load_lds(
          (const __attribute__((address_space(1))) unsigned int*)gh,
          (__attribute__((address_space(3))) unsigned int*)&Kh[row * 64], 16, 0, 0);
      __builtin_amdgcn_global_load_lds(
          (const __attribute__((address_space(1))) unsigned int*)gl,
          (__attribute__((address_space(3))) unsigned int*)&Kl[row * 64], 16, 0, 0);
    }
    __syncthreads();  // drains vmcnt(0): Q (kt=0) and K tiles visible
#pragma unroll
    for (int s = 0; s < 2; ++s) {
      const int ma = w * 16 + lm;
      const int ca = (s * 4 + lk) ^ (ma & 7);
      bhalf8 ah = *(const bhalf8*)&Qh[ma * 64 + ca * 8];
      bhalf8 al = *(const bhalf8*)&Ql[ma * 64 + ca * 8];
#pragma unroll
      for (int fn = 0; fn < 4; ++fn) {
        const int nb = fn * 16 + lm;
        const int cb2 = (s * 4 + lk) ^ (nb & 7);
        bhalf8 bh8 = *(const bhalf8*)&Kh[nb * 64 + cb2 * 8];
        bhalf8 bl8 = *(const bhalf8*)&Kl[nb * 64 + cb2 * 8];
        p[kt][fn] = __builtin_amdgcn_mfma_f32_16x16x32_bf16(ah, bh8, p[kt][fn], 0, 0, 0);
        p[kt][fn] = __builtin_amdgcn_mfma_f32_16x16x32_bf16(al, bh8, p[kt][fn], 0, 0, 0);
        p[kt][fn] = __builtin_amdgcn_mfma_f32_16x16x32_bf16(ah, bl8, p[kt][fn], 0, 0, 0);
      }
    }
#pragma unroll
    for (int fn = 0; fn < 4; ++fn)
#pragma unroll
      for (int j = 0; j < 4; ++j) {
        float e = __expf(p[kt][fn][j] * 0.125f);
        p[kt][fn][j] = e;
        zpart[j] += e;
      }
  }

  float invz[4];
#pragma unroll
  for (int j = 0; j < 4; ++j) {
    float z = zpart[j];
    z += __shfl_xor(z, 1);
    z += __shfl_xor(z, 2);
    z += __shfl_xor(z, 4);
    z += __shfl_xor(z, 8);
    invz[j] = 1.f / z;
  }

#pragma unroll
  for (int kt = 0; kt < 9; ++kt)
#pragma unroll
    for (int fn = 0; fn < 4; ++fn) {
      float cp = p[kt][fn][0] * invz[0] + p[kt][fn][1] * invz[1] +
                 p[kt][fn][2] * invz[2] + p[kt][fn][3] * invz[3];
      cp += __shfl_xor(cp, 16);
      cp += __shfl_xor(cp, 32);
      if (lk == 0) atomicAdd(&c_lds[kt * 64 + fn * 16 + lm], cp);
    }
  __syncthreads();
  for (int i = tid; i < L_; i += 256)
    atomicAdd(&c[(size_t)bh * L_ + i], c_lds[i]);
}

// ---------------------------------------------------------------------------
// Kernel 3: t[b, h*64+e] = sum_k c[b,h,k] * V[b,h,k,e]
// ---------------------------------------------------------------------------
__global__ void cv_kernel(const float* __restrict__ c,
                          const float* __restrict__ Vv,
                          float* __restrict__ t) {
  const int bh = blockIdx.x;
  const int e = threadIdx.x;
  const float* cb = c + (size_t)bh * L_;
  const float* Vb = Vv + (size_t)bh * L_ * HD_;
  float acc = 0.f;
  for (int k = 0; k < L_; ++k) acc = fmaf(cb[k], Vb[(size_t)k * HD_ + e], acc);
  int b = bh / H_, h = bh - (bh / H_) * H_;
  t[(size_t)b * D_ + h * HD_ + e] = acc;
}

// ---------------------------------------------------------------------------
// Kernel 4: s[b,d] = sum_d' t[b,d'] * Wproj[d,d'] + L*bproj[d]
// ---------------------------------------------------------------------------
__global__ __launch_bounds__(768) void proj_kernel(
    const float* __restrict__ t, const float* __restrict__ Wp,
    const float* __restrict__ bp, float* __restrict__ s) {
  __shared__ float tl[768];
  const int b = blockIdx.x, d = threadIdx.x;
  tl[d] = t[(size_t)b * D_ + d];
  __syncthreads();
  float acc = (float)L_ * bp[d];
  const float* wrow = Wp + (size_t)d * D_;
  for (int dp = 0; dp < D_; ++dp) acc = fmaf(tl[dp], wrow[dp], acc);
  s[(size_t)b * D_ + d] = acc;
}

// ---------------------------------------------------------------------------
// Kernel 5: sim[b,v] = sum_d s[b,d] * word_emd[v,d]. Memory-bound: streams
// 154 MB of w. 786 blocks x 64 v-rows, T14 async-stage split.
// ---------------------------------------------------------------------------
__global__ __launch_bounds__(256) void sim_kernel(
    const float* __restrict__ s, const float* __restrict__ w,
    float* __restrict__ sim) {
  __shared__ float sl[8][768];   // 24 KB
  __shared__ float wl[32][65];   // 8.125 KB, [d-in-chunk][row]
  const int tid = threadIdx.x;
  const int v0 = blockIdx.x * 64;

  for (int i = tid; i < 1536; i += 256)
    ((float4*)&sl[0][0])[i] = ((const float4*)s)[i];

  const int lr0 = tid >> 3;            // rows 0..31
  const int lr1 = lr0 + 32;            // rows 32..63
  const int lc4 = (tid & 7) << 2;      // 0,4,...,28
  int vr0 = v0 + lr0; if (vr0 >= V_) vr0 = V_ - 1;
  int vr1 = v0 + lr1; if (vr1 >= V_) vr1 = V_ - 1;
  const float* wp0 = w + (size_t)vr0 * D_ + lc4;
  const float* wp1 = w + (size_t)vr1 * D_ + lc4;

  float4 stg0 = *(const float4*)(wp0);
  float4 stg1 = *(const float4*)(wp1);

  const int cr = tid & 63;   // compute row (wave = one q)
  const int q = tid >> 6;    // d-quarter within chunk
  float acc[8] = {};

  for (int ch = 0; ch < 24; ++ch) {
    __syncthreads();  // previous chunk fully read
    wl[lc4 + 0][lr0] = stg0.x; wl[lc4 + 1][lr0] = stg0.y;
    wl[lc4 + 2][lr0] = stg0.z; wl[lc4 + 3][lr0] = stg0.w;
    wl[lc4 + 0][lr1] = stg1.x; wl[lc4 + 1][lr1] = stg1.y;
    wl[lc4 + 2][lr1] = stg1.z; wl[lc4 + 3][lr1] = stg1.w;
    __syncthreads();  // tile visible
    if (ch + 1 < 24) {
      stg0 = *(const float4*)(wp0 + (ch + 1) * 32);
      stg1 = *(const float4*)(wp1 + (ch + 1) * 32);
    }
    const int d0 = ch * 32;
#pragma unroll
    for (int g = 0; g < 2; ++g) {
      const int dd = q * 8 + g * 4;
      float w0 = wl[dd + 0][cr], w1 = wl[dd + 1][cr];
      float w2 = wl[dd + 2][cr], w3 = wl[dd + 3][cr];
#pragma unroll
      for (int b = 0; b < 8; ++b) {
        float4 sv = *(const float4*)&sl[b][d0 + dd];
        acc[b] = fmaf(w0, sv.x, acc[b]);
        acc[b] = fmaf(w1, sv.y, acc[b]);
        acc[b] = fmaf(w2, sv.z, acc[b]);
        acc[b] = fmaf(w3, sv.w, acc[b]);
      }
    }
  }

  __syncthreads();
  float* red = &wl[0][0];
  float4* rp = (float4*)&red[(q * 64 + cr) * 8];
  rp[0] = make_float4(acc[0], acc[1], acc[2], acc[3]);
  rp[1] = make_float4(acc[4], acc[5], acc[6], acc[7]);
  __syncthreads();
#pragma unroll
  for (int u = 0; u < 2; ++u) {
    int o = tid * 2 + u;
    int r = o >> 3, b = o & 7;
    float sum = red[(0 * 64 + r) * 8 + b] + red[(1 * 64 + r) * 8 + b] +
                red[(2 * 64 + r) * 8 + b] + red[(3 * 64 + r) * 8 + b];
    int v = v0 + r;
    if (v < V_) sim[(size_t)b * V_ + v] = sum;
  }
}

// ---------------------------------------------------------------------------
// Kernel 6a: per-chunk local top-10.
// ---------------------------------------------------------------------------
__global__ __launch_bounds__(256) void topk_stage1(
    const float* __restrict__ sim, float* __restrict__ cv,
    int* __restrict__ ci) {
  __shared__ float vals[CHUNK_SZ_];
  __shared__ float bv[256];
  __shared__ int bi[256];
  const int chunk = blockIdx.x, b = blockIdx.y, tid = threadIdx.x;
  const int base = chunk * CHUNK_SZ_;
  const float* row = sim + (size_t)b * V_;
  for (int i = tid; i < CHUNK_SZ_; i += 256) {
    int v = base + i;
    vals[i] = (v < V_) ? row[v] : -INFINITY;
  }
  __syncthreads();
  for (int k = 0; k < TOPK_; ++k) {
    float best = -INFINITY;
    int besti = CHUNK_SZ_;
    for (int i = tid; i < CHUNK_SZ_; i += 256) {
      float x = vals[i];
      if (x > best) { best = x; besti = i; }
    }
    bv[tid] = best; bi[tid] = besti;
    __syncthreads();
    for (int off = 128; off > 0; off >>= 1) {
      if (tid < off) {
        float ov = bv[tid + off]; int oi = bi[tid + off];
        if (ov > bv[tid] || (ov == bv[tid] && oi < bi[tid])) {
          bv[tid] = ov; bi[tid] = oi;
        }
      }
      __syncthreads();
    }
    if (tid == 0) {
      int slot = (b * CHUNKS_ + chunk) * TOPK_ + k;
      cv[slot] = bv[0];
      ci[slot] = base + bi[0];
      if (bi[0] < CHUNK_SZ_) vals[bi[0]] = -INFINITY;
    }
    __syncthreads();
  }
}

// ---------------------------------------------------------------------------
// Kernel 6b: reduce 64 chunks x 10 candidates -> global top-10 per batch.
// ---------------------------------------------------------------------------
__global__ __launch_bounds__(256) void topk_stage2(
    const float* __restrict__ cv, const int* __restrict__ ci,
    int* __restrict__ topk) {
  const int NC = CHUNKS_ * TOPK_;  // 640
  __shared__ float vals[CHUNKS_ * TOPK_];
  __shared__ int gidx[CHUNKS_ * TOPK_];
  __shared__ float bv[256];
  __shared__ int bi[256];
  const int b = blockIdx.x, tid = threadIdx.x;
  for (int i = tid; i < NC; i += 256) {
    vals[i] = cv[(size_t)b * NC + i];
    gidx[i] = ci[(size_t)b * NC + i];
  }
  __syncthreads();
  for (int k = 0; k < TOPK_; ++k) {
    float best = -INFINITY;
    int bslot = NC;
    for (int i = tid; i < NC; i += 256) {
      float x = vals[i];
      if (x > best) { best = x; bslot = i; }
    }
    bv[tid] = best; bi[tid] = bslot;
    __syncthreads();
    for (int off = 128; off > 0; off >>= 1) {
      if (tid < off) {
        float ov = bv[tid + off]; int oi = bi[tid + off];
        if (ov > bv[tid] || (ov == bv[tid] && oi < bi[tid])) {
          bv[tid] = ov; bi[tid] = oi;
        }
      }
      __syncthreads();
    }
    if (tid == 0) {
      int slot = bi[0];
      topk[b * TOPK_ + k] = (slot < NC) ? gidx[slot] : 0;
      if (slot < NC) vals[slot] = -INFINITY;
    }
    __syncthreads();
  }
}

// ---------------------------------------------------------------------------
// Kernel 7: gather word_emd rows -> output [B, K, D]
// ---------------------------------------------------------------------------
__global__ void gather_kernel(const int* __restrict__ topk,
                              const float* __restrict__ w,
                              float* __restrict__ out) {
  const int bk = blockIdx.x;
  const int idx = topk[bk];
  const int t4 = threadIdx.x << 2;
  *(float4*)(out + (size_t)bk * D_ + t4) =
      *(const float4*)(w + (size_t)idx * D_ + t4);
}

extern "C" void kernel_launch(void* const* d_in, const int* in_sizes, int n_in,
                              void* d_out, int out_size, void* d_ws,
                              size_t ws_size, hipStream_t stream) {
  const float* prompt = (const float*)d_in[0];
  const float* enc    = (const float*)d_in[1];
  const float* wemd   = (const float*)d_in[2];
  const float* Wqkv   = (const float*)d_in[3];
  const float* Wproj  = (const float*)d_in[4];
  const float* bproj  = (const float*)d_in[5];
  float* out = (float*)d_out;

  float* ws = (float*)d_ws;
  const size_t QSZ = (size_t)B_ * H_ * L_ * HD_;  // 3,538,944
  float* Vv   = ws;                        // fp32 V
  float* c    = Vv + QSZ;                  // 96*576 = 55,296
  float* t    = c + (size_t)B_ * H_ * L_;  // 6144
  float* s    = t + (size_t)B_ * D_;       // 6144
  float* sim  = s + (size_t)B_ * D_;       // 8*50257 = 402,056
  float* cand_v = sim + (size_t)B_ * V_;   // 8*640 = 5120
  int* cand_i   = (int*)(cand_v + (size_t)B_ * CHUNKS_ * TOPK_);
  int* topk     = cand_i + (size_t)B_ * CHUNKS_ * TOPK_;
  unsigned short* Qhi = (unsigned short*)(topk + B_ * TOPK_ + 64);
  unsigned short* Qlo = Qhi + QSZ;
  unsigned short* Khi = Qlo + QSZ;
  unsigned short* Klo = Khi + QSZ;
  unsigned short* Ahi = Klo + QSZ;
  unsigned short* Alo = Ahi + (size_t)M_QKV * K_QKV;
  unsigned short* Bhi = Alo + (size_t)M_QKV * K_QKV;
  unsigned short* Blo = Bhi + (size_t)N_QKV * K_QKV;

  hipMemsetAsync(c, 0, (size_t)B_ * H_ * L_ * sizeof(float), stream);

  const int NCONV = (M_QKV * K_QKV + N_QKV * K_QKV) / 4;  // 1,327,104
  convert_split<<<(NCONV + 255) / 256, 256, 0, stream>>>(
      prompt, enc, Wqkv, Ahi, Alo, Bhi, Blo);
  qkv_mfma<<<648, 256, 0, stream>>>(
      Ahi, Alo, Bhi, Blo, Qhi, Qlo, Khi, Klo, Vv);
  attn_mfma<<<dim3(9, 96), 256, 0, stream>>>(Qhi, Qlo, Khi, Klo, c);
  cv_kernel<<<96, 64, 0, stream>>>(c, Vv, t);
  proj_kernel<<<8, 768, 0, stream>>>(t, Wproj, bproj, s);
  sim_kernel<<<NVB_, 256, 0, stream>>>(s, wemd, sim);
  topk_stage1<<<dim3(CHUNKS_, B_), 256, 0, stream>>>(sim, cand_v, cand_i);
  topk_stage2<<<B_, 256, 0, stream>>>(cand_v, cand_i, topk);
  gather_kernel<<<80, 192, 0, stream>>>(topk, wemd, out);
}